// Round 12
// baseline (659.244 us; speedup 1.0000x reference)
//
#include <hip/hip_runtime.h>
#include <math.h>

// ---------------- problem constants ----------------
#define Bn_   32
#define Ln_   8192
#define LCn   8184            // L - 8
#define NLn   2
#define NCHn  328             // scan chunks (328 % 4 == 0 -> each block owns one group; 82 blocks/group)
#define CHn   25              // chunk length (328*25 = 8200 >= 8184, tail guarded)
#define NGn   24              // sequence groups (96 seqs / 4 per wave)
#define BLKPG 82              // blocks per group = NCHn/4

static constexpr long N_BL = (long)Bn_ * LCn;            // 261888
static constexpr long NCAR = (long)NGn * NCHn * 256;     // 2,015,232 carry floats (< 8*N_BL)

// ---- ws layout (float offsets), total 48N = 50.28 MB ----
static constexpr long OFF_H    = 0;                  // 12N  (mamba hidden, layer-0 output)
static constexpr long OFF_REC  = 12*N_BL;            // 24N  (rec = [u0..3, lg0..3] per (m,b,t))
static constexpr long OFF_YB   = 36*N_BL;            // 12N  (scan y, [m][b][t][d]); Ap aliases first 8N
static constexpr long OFF_PART = OFF_REC;            // part aliases rec (dead after scanD l=1)
// d_out scratch: Sv [4N,12N) ; gcnt ints at sv+2020000 (above NCAR)

#define L2E_  1.4426950408889634f     // log2(e)
#define LN2_  0.6931471805599453f     // ln(2)
#define EXP2_(x) __builtin_amdgcn_exp2f(x)
#define LOG2_(x) __builtin_amdgcn_logf(x)

__device__ __forceinline__ float si_(float v) {
    float e = EXP2_(-v * L2E_);
    return v * __builtin_amdgcn_rcpf(1.f + e);
}

__device__ __forceinline__ float sel4(float4 v, int d) {
    return (d & 2) ? ((d & 1) ? v.w : v.z) : ((d & 1) ? v.y : v.x);
}

__device__ __forceinline__ float rowsum16(float p) {
    p += __int_as_float(__builtin_amdgcn_update_dpp(0, __float_as_int(p), 0x128, 0xF, 0xF, true)); // row_ror:8
    p += __int_as_float(__builtin_amdgcn_update_dpp(0, __float_as_int(p), 0x124, 0xF, 0xF, true)); // row_ror:4
    p += __int_as_float(__builtin_amdgcn_update_dpp(0, __float_as_int(p), 0x122, 0xF, 0xF, true)); // row_ror:2
    p += __int_as_float(__builtin_amdgcn_update_dpp(0, __float_as_int(p), 0x121, 0xF, 0xF, true)); // row_ror:1
    return p;
}

// xin(p) = [z0, xd, z0_flip, xd_flip] recomputed from x (x is 1MB -> L2-hot)
__device__ __forceinline__ float4 compute_xin(const float* __restrict__ xb, int p) {
    const float c0 = 1.f/280.f, c1 = -4.f/105.f, c2 = 0.2f, c3 = -0.8f,
                c5 = 0.8f, c6 = -0.2f, c7 = 4.f/105.f, c8 = -1.f/280.f;
    float xd  = c0*xb[p]   + c1*xb[p+1] + c2*xb[p+2] + c3*xb[p+3]
              + c5*xb[p+5] + c6*xb[p+6] + c7*xb[p+7] + c8*xb[p+8];
    int tf = LCn - 1 - p;
    float xdf = c0*xb[tf]   + c1*xb[tf+1] + c2*xb[tf+2] + c3*xb[tf+3]
              + c5*xb[tf+5] + c6*xb[tf+6] + c7*xb[tf+7] + c8*xb[tf+8];
    float4 v; v.x = xb[p+4]; v.y = xd; v.z = xb[tf+4]; v.w = xdf;
    return v;
}

__device__ __forceinline__ float4 rms_xproj(float4 hv, const float* __restrict__ wn,
                                            const float* __restrict__ W) {
    float ms = (hv.x*hv.x + hv.y*hv.y + hv.z*hv.z + hv.w*hv.w)*0.25f + 1e-5f;
    float rs = __builtin_amdgcn_rsqf(ms);
    float hn0 = hv.x*rs*wn[0], hn1 = hv.y*rs*wn[1];
    float hn2 = hv.z*rs*wn[2], hn3 = hv.w*rs*wn[3];
    float4 o;
    o.x = W[0]*hn0  + W[1]*hn1  + W[2]*hn2  + W[3]*hn3;
    o.y = W[4]*hn0  + W[5]*hn1  + W[6]*hn2  + W[7]*hn3;
    o.z = W[8]*hn0  + W[9]*hn1  + W[10]*hn2 + W[11]*hn3;
    o.w = W[12]*hn0 + W[13]*hn1 + W[14]*hn2 + W[15]*hn3;
    return o;
}

__device__ __forceinline__ void conv_lg_store(const float4* xp, int k, int ml,
                                              const float* __restrict__ cw,
                                              const float* __restrict__ cbv,
                                              const float* __restrict__ xpw,
                                              const float* __restrict__ dtw,
                                              const float* __restrict__ dtb,
                                              float* __restrict__ rp) {
    const float* wc = cw  + ml*16;
    const float* bc = cbv + ml*4;
    float acc0 = bc[0], acc1 = bc[1], acc2 = bc[2], acc3 = bc[3];
#pragma unroll
    for (int j = 0; j < 4; j++) {
        float4 xv = xp[k + j];
        acc0 = fmaf(xv.x, wc[0*4+j], acc0);
        acc1 = fmaf(xv.y, wc[1*4+j], acc1);
        acc2 = fmaf(xv.z, wc[2*4+j], acc2);
        acc3 = fmaf(xv.w, wc[3*4+j], acc3);
    }
    float4 o;
    o.x = si_(acc0); o.y = si_(acc1); o.z = si_(acc2); o.w = si_(acc3);
    const float* P = xpw + (long)ml*33*4;
    float dtr = o.x*P[0] + o.y*P[1] + o.z*P[2] + o.w*P[3];
    const float* dwv = dtw + ml*4;
    const float* dbv = dtb + ml*4;
    float4 lg;
    lg.x = LOG2_(1.f + EXP2_(fmaf(dtr, dwv[0], dbv[0]) * L2E_));
    lg.y = LOG2_(1.f + EXP2_(fmaf(dtr, dwv[1], dbv[1]) * L2E_));
    lg.z = LOG2_(1.f + EXP2_(fmaf(dtr, dwv[2], dbv[2]) * L2E_));
    lg.w = LOG2_(1.f + EXP2_(fmaf(dtr, dwv[3], dbv[3]) * L2E_));
    *(float4*)rp       = o;
    *(float4*)(rp + 4) = lg;
}

// ---------------- 1. fused deriv + rmsnorm0 + in_proj0 + conv0 + silu + lg ----------------
__global__ __launch_bounds__(256)
void k_pre0(const float* __restrict__ x,
            const float* __restrict__ ipw, const float* __restrict__ cw,
            const float* __restrict__ cbv, const float* __restrict__ nw,
            const float* __restrict__ xpw, const float* __restrict__ dtw,
            const float* __restrict__ dtb, float* __restrict__ rec,
            int* __restrict__ gcnt) {
    if (blockIdx.x == 0 && threadIdx.x < NGn) gcnt[threadIdx.x] = 0;  // arm scanBC counters
    __shared__ float4 xp[259];
    int blk = blockIdx.x;
    int m = blk >> 10, bb = (blk >> 5) & 31, tile = blk & 31;
    int ml = m*NLn;                 // l = 0
    int t0 = tile << 8, k = threadIdx.x;
    int t  = t0 + k;
    const float* xb = x + (long)bb*Ln_;
    const float* W  = ipw + (long)ml*32;
    const float* wn = nw  + ml*4;
    auto G = [&](int p) -> float4 {
        float4 o; o.x = o.y = o.z = o.w = 0.f;
        if (p >= 0 && p < LCn) o = rms_xproj(compute_xin(xb, p), wn, W);
        return o;
    };
    xp[k + 3] = G(t);
    if (k < 3) xp[k] = G(t0 + k - 3);
    __syncthreads();
    if (t >= LCn) return;
    conv_lg_store(xp, k, ml, cw, cbv, xpw, dtw, dtb,
                  rec + ((long)m*N_BL + (long)bb*LCn + t)*8);
}

// ---------------- 2. fused post0 (writes h) + rmsnorm1 + in_proj1 + conv1 + silu + lg ----------------
__global__ __launch_bounds__(256)
void k_mid(const float* __restrict__ x, const float* __restrict__ yb,
           float* __restrict__ hout,
           const float* __restrict__ ipw, const float* __restrict__ cw,
           const float* __restrict__ cbv, const float* __restrict__ nw,
           const float* __restrict__ xpw, const float* __restrict__ dtw,
           const float* __restrict__ dtb, const float* __restrict__ opw,
           float* __restrict__ rec, int* __restrict__ gcnt) {
    if (blockIdx.x == 0 && threadIdx.x < NGn) gcnt[threadIdx.x] = 0;  // re-arm for l=1
    __shared__ float4 xp[259];
    int blk = blockIdx.x;
    int m = blk >> 10, bb = (blk >> 5) & 31, tile = blk & 31;
    int ml0 = m*NLn, ml1 = ml0 + 1;
    int t0 = tile << 8, k = threadIdx.x;
    int t  = t0 + k;
    const float* xb  = x + (long)bb*Ln_;
    const float* wn0 = nw + ml0*4;
    const float* Wr  = ipw + (long)(ml0*8 + 4)*4;
    const float* O   = opw + ml0*16;
    const float* wn1 = nw + ml1*4;
    const float* W1  = ipw + (long)ml1*32;
    auto H = [&](int p) -> float4 {
        float4 hv = compute_xin(xb, p);
        float ms = (hv.x*hv.x + hv.y*hv.y + hv.z*hv.z + hv.w*hv.w)*0.25f + 1e-5f;
        float rs = __builtin_amdgcn_rsqf(ms);
        float hn0 = hv.x*rs*wn0[0], hn1 = hv.y*rs*wn0[1];
        float hn2 = hv.z*rs*wn0[2], hn3 = hv.w*rs*wn0[3];
        float4 yv = *(const float4*)(yb + ((long)m*N_BL + (long)bb*LCn + p)*4);
        float g0 = yv.x * si_(Wr[0]*hn0  + Wr[1]*hn1  + Wr[2]*hn2  + Wr[3]*hn3);
        float g1 = yv.y * si_(Wr[4]*hn0  + Wr[5]*hn1  + Wr[6]*hn2  + Wr[7]*hn3);
        float g2 = yv.z * si_(Wr[8]*hn0  + Wr[9]*hn1  + Wr[10]*hn2 + Wr[11]*hn3);
        float g3 = yv.w * si_(Wr[12]*hn0 + Wr[13]*hn1 + Wr[14]*hn2 + Wr[15]*hn3);
        float4 o;
        o.x = O[0]*g0  + O[1]*g1  + O[2]*g2  + O[3]*g3  + hv.x;
        o.y = O[4]*g0  + O[5]*g1  + O[6]*g2  + O[7]*g3  + hv.y;
        o.z = O[8]*g0  + O[9]*g1  + O[10]*g2 + O[11]*g3 + hv.z;
        o.w = O[12]*g0 + O[13]*g1 + O[14]*g2 + O[15]*g3 + hv.w;
        return o;
    };
    float4 zf; zf.x = zf.y = zf.z = zf.w = 0.f;
    if (t < LCn) {
        float4 hnew = H(t);
        *(float4*)(hout + ((long)m*N_BL + (long)bb*LCn + t)*4) = hnew;
        xp[k + 3] = rms_xproj(hnew, wn1, W1);
    } else {
        xp[k + 3] = zf;
    }
    if (k < 3) {
        int p = t0 + k - 3;
        xp[k] = (p >= 0) ? rms_xproj(H(p), wn1, W1) : zf;
    }
    __syncthreads();
    if (t >= LCn) return;
    conv_lg_store(xp, k, ml1, cw, cbv, xpw, dtw, dtb,
                  rec + ((long)m*N_BL + (long)bb*LCn + t)*8);
}

// ---------------- 3a. fused scan B+C: carries, then last-block-per-group does the prefix ----------------
#define SCANC_G 8
__global__ __launch_bounds__(256, 8)
void k_scanBC(const float* __restrict__ rec, int l,
              const float* __restrict__ xpw, const float* __restrict__ Alog,
              float* __restrict__ Ap, float* __restrict__ Sv,
              int* __restrict__ gcnt) {
    int wid  = blockIdx.x*4 + (threadIdx.x >> 6);
    int lane = threadIdx.x & 63;
    int chunk = wid % NCHn;
    int g     = wid / NCHn;         // same for all 4 waves of a block (NCHn%4==0)
    int m = g >> 3;
    int s = lane >> 4, n = lane & 15;
    int bb = (g & 7)*4 + s;
    int ml = m*NLn + l;
    const float* P  = xpw + (long)ml*33*4;
    const float* PB = P + (1+n)*4;
    float pb0 = PB[0]*LN2_, pb1 = PB[1]*LN2_, pb2 = PB[2]*LN2_, pb3 = PB[3]*LN2_;
    const float* AL = Alog + (long)ml*64 + n;
    float4 Av;
    Av.x = -EXP2_(AL[0]  * L2E_);
    Av.y = -EXP2_(AL[16] * L2E_);
    Av.z = -EXP2_(AL[32] * L2E_);
    Av.w = -EXP2_(AL[48] * L2E_);
    const float* rb = rec + ((long)m*N_BL + (long)bb*LCn)*8;
    int t0 = chunk*CHn, t1 = min(t0 + CHn, LCn);
    float4 ap; ap.x = ap.y = ap.z = ap.w = 1.f;
    float4 sv; sv.x = sv.y = sv.z = sv.w = 0.f;
#pragma unroll 4
    for (int t = t0; t < t1; t++) {
        float4 u  = *(const float4*)(rb + (long)t*8);
        float4 lg = *(const float4*)(rb + (long)t*8 + 4);
        float Bv = u.x*pb0 + u.y*pb1 + u.z*pb2 + u.w*pb3;
        float4 a;
        a.x = EXP2_(lg.x * Av.x); a.y = EXP2_(lg.y * Av.y);
        a.z = EXP2_(lg.z * Av.z); a.w = EXP2_(lg.w * Av.w);
        sv.x = fmaf(a.x, sv.x, lg.x*u.x*Bv);
        sv.y = fmaf(a.y, sv.y, lg.y*u.y*Bv);
        sv.z = fmaf(a.z, sv.z, lg.z*u.z*Bv);
        sv.w = fmaf(a.w, sv.w, lg.w*u.w*Bv);
        ap.x *= a.x; ap.y *= a.y; ap.z *= a.z; ap.w *= a.w;
    }
    long ci = (((long)g*NCHn + chunk)*64 + lane)*4;
    *(float4*)(Ap + ci) = ap;
    *(float4*)(Sv + ci) = sv;
    // ---- last block of this group runs the prefix scan (scanC) ----
    __threadfence();                 // release: push carries to device scope
    __syncthreads();
    __shared__ int lastf;
    if (threadIdx.x == 0)
        lastf = (atomicAdd(&gcnt[g], 1) == BLKPG - 1);
    __syncthreads();
    if (!lastf) return;
    __threadfence();                 // acquire: invalidate stale remote lines
    int tid = threadIdx.x;           // 256 states of group g
    long base = (long)g*NCHn*256 + tid;
    const int NFULL = NCHn / SCANC_G;        // 41, exact (328 = 41*8)
    float h = 0.f;
    float ca[SCANC_G], cs[SCANC_G], na[SCANC_G], ns[SCANC_G];
#pragma unroll
    for (int j = 0; j < SCANC_G; j++) {
        ca[j] = Ap[base + (long)j*256];
        cs[j] = Sv[base + (long)j*256];
    }
    for (int grp = 0; grp < NFULL; grp++) {
        long gb = base + (long)grp*SCANC_G*256;
        if (grp + 1 < NFULL) {
            long nb = gb + (long)SCANC_G*256;
#pragma unroll
            for (int j = 0; j < SCANC_G; j++) {
                na[j] = Ap[nb + (long)j*256];
                ns[j] = Sv[nb + (long)j*256];
            }
        }
#pragma unroll
        for (int j = 0; j < SCANC_G; j++) {
            Sv[gb + (long)j*256] = h;            // exclusive prefix: h0 for chunk
            h = fmaf(ca[j], h, cs[j]);
        }
#pragma unroll
        for (int j = 0; j < SCANC_G; j++) { ca[j] = na[j]; cs[j] = ns[j]; }
    }
    if (tid == 0) gcnt[g] = 0;       // self-clean
}

// ---------------- 3b. scan phase D: final scan + y (D-term folded) ----------------
__global__ __launch_bounds__(256, 8)
void k_scanD(const float* __restrict__ rec, float* __restrict__ yb, int l,
             const float* __restrict__ xpw, const float* __restrict__ Alog,
             const float* __restrict__ H0, const float* __restrict__ Dp) {
    int wid  = blockIdx.x*4 + (threadIdx.x >> 6);
    int lane = threadIdx.x & 63;
    int chunk = wid % NCHn;
    int g     = wid / NCHn;
    int m = g >> 3;
    int s = lane >> 4, n = lane & 15;
    int bb = (g & 7)*4 + s;
    int ml = m*NLn + l;
    const float* P  = xpw + (long)ml*33*4;
    const float* PB = P + (1+n)*4;
    float pb0 = PB[0]*LN2_, pb1 = PB[1]*LN2_, pb2 = PB[2]*LN2_, pb3 = PB[3]*LN2_;
    const float* PC = P + (17+n)*4;
    float pc0 = PC[0], pc1 = PC[1], pc2 = PC[2], pc3 = PC[3];
    const float* AL = Alog + (long)ml*64 + n;
    float4 Av;
    Av.x = -EXP2_(AL[0]  * L2E_);
    Av.y = -EXP2_(AL[16] * L2E_);
    Av.z = -EXP2_(AL[32] * L2E_);
    Av.w = -EXP2_(AL[48] * L2E_);
    float Dd = Dp[ml*4 + (n & 3)];
    float4 h = *(const float4*)(H0 + (((long)g*NCHn + chunk)*64 + lane)*4);
    const float* rb = rec + ((long)m*N_BL + (long)bb*LCn)*8;
    float* ym = yb + ((long)m*N_BL + (long)bb*LCn)*4;   // [m][b][t][d]
    int t0 = chunk*CHn, t1 = min(t0 + CHn, LCn);
#pragma unroll 4
    for (int t = t0; t < t1; t++) {
        float4 u  = *(const float4*)(rb + (long)t*8);
        float4 lg = *(const float4*)(rb + (long)t*8 + 4);
        float Bv = u.x*pb0 + u.y*pb1 + u.z*pb2 + u.w*pb3;
        float Cv = u.x*pc0 + u.y*pc1 + u.z*pc2 + u.w*pc3;
        float4 a;
        a.x = EXP2_(lg.x * Av.x); a.y = EXP2_(lg.y * Av.y);
        a.z = EXP2_(lg.z * Av.z); a.w = EXP2_(lg.w * Av.w);
        h.x = fmaf(a.x, h.x, lg.x*u.x*Bv);
        h.y = fmaf(a.y, h.y, lg.y*u.y*Bv);
        h.z = fmaf(a.z, h.z, lg.z*u.z*Bv);
        h.w = fmaf(a.w, h.w, lg.w*u.w*Bv);
        float px = rowsum16(h.x * Cv);
        float py = rowsum16(h.y * Cv);
        float pz = rowsum16(h.z * Cv);
        float pw = rowsum16(h.w * Cv);
        if (n < 4) {
            float out = (n & 2) ? ((n & 1) ? pw : pz) : ((n & 1) ? py : px);
            float ud  = sel4(u, n);
            ym[(long)t*4 + n] = fmaf(ud, Dd, out);
        }
    }
}

// ---------------- 4. fused tail: post1+head (raw in LDS) + smooth + yhat + pen partials ----------------
__global__ __launch_bounds__(256)
void k_tail(const float* __restrict__ x, const float* __restrict__ hin,
            const float* __restrict__ yb,
            const float* __restrict__ ipw, const float* __restrict__ nw,
            const float* __restrict__ opw,
            const float* __restrict__ ww, const float* __restrict__ wb,
            const float* __restrict__ gw, const float* __restrict__ gb,
            const float* __restrict__ dw, const float* __restrict__ dbp,
            const float* __restrict__ bp,
            float* __restrict__ dout, double* __restrict__ part) {
    int b    = blockIdx.x >> 5;     // 32 b
    int tile = blockIdx.x & 31;     // 32 tiles of 256
    int k    = threadIdx.x;
    int t0   = tile << 8;
    __shared__ float ro_[266], rg_[266], rd_[266];   // raw for t in [t0-4, t0+262)
    __shared__ float so_[257], sg_[257], sd_[257];
    // compute raw (postHead) for halo entry e: t = t0-4+e
    auto rawcalc = [&](int e) {
        int t = t0 - 4 + e;
        float vo = 0.f, vg = 0.f, vd = 0.f;
        if (t >= 0 && t < LCn) {
            long r = (long)b*LCn + t;
            float4 om[3];
#pragma unroll
            for (int m = 0; m < 3; m++) {
                int ml = m*NLn + 1;
                float4 hv = *(const float4*)(hin + (long)m*4*N_BL + r*4);
                float ms = (hv.x*hv.x + hv.y*hv.y + hv.z*hv.z + hv.w*hv.w)*0.25f + 1e-5f;
                float rs = __builtin_amdgcn_rsqf(ms);
                const float* wn = nw + ml*4;
                float hn0 = hv.x*rs*wn[0], hn1 = hv.y*rs*wn[1];
                float hn2 = hv.z*rs*wn[2], hn3 = hv.w*rs*wn[3];
                const float* W = ipw + (long)(ml*8 + 4)*4;
                float4 yv = *(const float4*)(yb + ((long)m*N_BL + r)*4);
                float g0 = yv.x * si_(W[0]*hn0  + W[1]*hn1  + W[2]*hn2  + W[3]*hn3);
                float g1 = yv.y * si_(W[4]*hn0  + W[5]*hn1  + W[6]*hn2  + W[7]*hn3);
                float g2 = yv.z * si_(W[8]*hn0  + W[9]*hn1  + W[10]*hn2 + W[11]*hn3);
                float g3 = yv.w * si_(W[12]*hn0 + W[13]*hn1 + W[14]*hn2 + W[15]*hn3);
                const float* O = opw + ml*16;
                float4 o;
                o.x = O[0]*g0  + O[1]*g1  + O[2]*g2  + O[3]*g3  + hv.x;
                o.y = O[4]*g0  + O[5]*g1  + O[6]*g2  + O[7]*g3  + hv.y;
                o.z = O[8]*g0  + O[9]*g1  + O[10]*g2 + O[11]*g3 + hv.z;
                o.w = O[12]*g0 + O[13]*g1 + O[14]*g2 + O[15]*g3 + hv.w;
                om[m] = o;
            }
            float4* c = (float4*)(dout + N_BL + r*12);   // halo double-writes are identical
            c[0] = om[0]; c[1] = om[1]; c[2] = om[2];
            vo = om[0].x*ww[0] + om[0].y*ww[1] + om[0].z*ww[2] + om[0].w*ww[3] + wb[0];
            vg = (om[1].x*gw[0] + om[1].y*gw[1] + om[1].z*gw[2] + om[1].w*gw[3] + gb[0]) / 1000.0f;
            vd = fmaxf(om[2].x*dw[0] + om[2].y*dw[1] + om[2].z*dw[2] + om[2].w*dw[3] + dbp[0], 0.f);
        }
        ro_[e] = vo; rg_[e] = vg; rd_[e] = vd;
    };
    rawcalc(k);
    if (k < 10) rawcalc(k + 256);
    __syncthreads();
    // smooth: window for t=t0+kk is LDS e in [kk, kk+9] (zeros outside valid range)
    auto smo = [&](int kk, float& o, float& g, float& d) {
        o = g = d = 0.f;
#pragma unroll
        for (int j = 0; j < 10; j++) {
            o += fabsf(ro_[kk + j]); g += rg_[kk + j]; d += fabsf(rd_[kk + j]);
        }
        o *= 0.1f; g *= 0.1f; d *= 0.1f;
    };
    float so, sg, sd;
    smo(k, so, sg, sd);
    so_[k] = so; sg_[k] = sg; sd_[k] = sd;
    if (k == 0) {
        float a1, b1, c1;
        smo(256, a1, b1, c1);
        so_[256] = a1; sg_[256] = b1; sd_[256] = c1;
    }
    __syncthreads();
    int t = t0 + k;
    if (t < LCn) {
        const float* xb = x + (long)b * Ln_;
        const float c0 = 1.f/280.f, c1 = -4.f/105.f, c2 = 0.2f, c3 = -0.8f,
                    c5 = 0.8f, c6 = -0.2f, c7 = 4.f/105.f, c8 = -1.f/280.f;
        float xd  = c0*xb[t]   + c1*xb[t+1] + c2*xb[t+2] + c3*xb[t+3]
                  + c5*xb[t+5] + c6*xb[t+6] + c7*xb[t+7] + c8*xb[t+8];
        float z1 = xb[t+4];
        float z2 = xd / 0.0001f;
        float bq = fmaxf(bp[0], 0.f) / 1000.0f;
        dout[(long)b*LCn + t] = -so*so*z1 + sg*z2 - bq*z1*z1*z2 - sd;
    }
    double v[6] = {0,0,0,0,0,0};
    if (t >= 1 && t <= LCn - 2) {
        double go = (double)so_[k+1] - (double)so_[k];
        double gg = (double)sg_[k+1] - (double)sg_[k];
        double gd = (double)sd_[k+1] - (double)sd_[k];
        v[0] = go; v[1] = go*go;
        v[2] = gg; v[3] = gg*gg;
        v[4] = gd; v[5] = gd*gd;
    }
#pragma unroll
    for (int j = 0; j < 6; j++) {
        for (int off = 32; off > 0; off >>= 1)
            v[j] += __shfl_down(v[j], off, 64);
    }
    __shared__ double wsum[4][6];
    int w = threadIdx.x >> 6;
    if ((threadIdx.x & 63) == 0) {
#pragma unroll
        for (int j = 0; j < 6; j++) wsum[w][j] = v[j];
    }
    __syncthreads();
    if (threadIdx.x == 0) {
        double sarr[6];
#pragma unroll
        for (int j = 0; j < 6; j++)
            sarr[j] = wsum[0][j] + wsum[1][j] + wsum[2][j] + wsum[3][j];
        long pb = (((long)0*32 + b)*32 + tile)*2;
        part[pb]   = sarr[0]; part[pb+1] = sarr[1];
        pb = (((long)1*32 + b)*32 + tile)*2;
        part[pb]   = sarr[2]; part[pb+1] = sarr[3];
        pb = (((long)2*32 + b)*32 + tile)*2;
        part[pb]   = sarr[4]; part[pb+1] = sarr[5];
    }
}

// ---------------- 5. penalty finalize ----------------
__global__ void k_pen2(const double* __restrict__ part, float* __restrict__ pout) {
    int tid = threadIdx.x;          // 128 threads, 96 active
    double var = 0.0;
    if (tid < 96) {
        int which = tid / 32, b = tid % 32;
        double su = 0.0, s2 = 0.0;
        for (int tl = 0; tl < 32; tl++) {
            const double* p = part + (((long)which*32 + b)*32 + tl)*2;
            su += p[0]; s2 += p[1];
        }
        const double N = (double)(LCn - 2);
        var = (s2 - su*su/N) / (N - 1.0);
    }
    __shared__ double sh[128];
    sh[tid] = var;
    __syncthreads();
    for (int o = 64; o > 0; o >>= 1) {
        if (tid < o) sh[tid] += sh[tid + o];
        __syncthreads();
    }
    if (tid == 0) pout[0] = (float)(sh[0] / 96.0);
}

// ---------------- launch ----------------
extern "C" void kernel_launch(void* const* d_in, const int* in_sizes, int n_in,
                              void* d_out, int out_size, void* d_ws, size_t ws_size,
                              hipStream_t stream) {
    const float* x    = (const float*)d_in[0];
    const float* ipw  = (const float*)d_in[1];
    const float* cw   = (const float*)d_in[2];
    const float* cbv  = (const float*)d_in[3];
    const float* xpw  = (const float*)d_in[4];
    const float* dtw  = (const float*)d_in[5];
    const float* dtb  = (const float*)d_in[6];
    const float* Alog = (const float*)d_in[7];
    const float* Dp   = (const float*)d_in[8];
    const float* nw   = (const float*)d_in[9];
    const float* opw  = (const float*)d_in[10];
    const float* ww   = (const float*)d_in[11];
    const float* wb   = (const float*)d_in[12];
    const float* gw   = (const float*)d_in[13];
    const float* gb   = (const float*)d_in[14];
    const float* dw   = (const float*)d_in[15];
    const float* dbp  = (const float*)d_in[16];
    const float* bp   = (const float*)d_in[17];

    float* ws   = (float*)d_ws;
    float* h    = ws + OFF_H;
    float* rec  = ws + OFF_REC;
    float* yb   = ws + OFF_YB;
    float* ap   = yb;                 // Ap aliases YB[0,8N) (dead before scanD writes y)
    double* part = (double*)(ws + OFF_PART);   // aliases rec (dead after scanD l=1)
    float* dout = (float*)d_out;
    float* sv   = dout + 4*N_BL;      // d_out scratch (8N region), last read by scanD l=1
    int*   gcnt = (int*)(sv + 2020000);  // above NCAR=2,015,232; zeroed by pre0/mid

    hipLaunchKernelGGL(k_pre0, dim3(3072), dim3(256), 0, stream,
                       x, ipw, cw, cbv, nw, xpw, dtw, dtb, rec, gcnt);
    hipLaunchKernelGGL(k_scanBC, dim3(NGn*NCHn/4), dim3(256), 0, stream,
                       rec, 0, xpw, Alog, ap, sv, gcnt);
    hipLaunchKernelGGL(k_scanD, dim3(NGn*NCHn/4), dim3(256), 0, stream,
                       rec, yb, 0, xpw, Alog, sv, Dp);
    hipLaunchKernelGGL(k_mid, dim3(3072), dim3(256), 0, stream,
                       x, yb, h, ipw, cw, cbv, nw, xpw, dtw, dtb, opw, rec, gcnt);
    hipLaunchKernelGGL(k_scanBC, dim3(NGn*NCHn/4), dim3(256), 0, stream,
                       rec, 1, xpw, Alog, ap, sv, gcnt);
    hipLaunchKernelGGL(k_scanD, dim3(NGn*NCHn/4), dim3(256), 0, stream,
                       rec, yb, 1, xpw, Alog, sv, Dp);
    hipLaunchKernelGGL(k_tail, dim3(1024), dim3(256), 0, stream,
                       x, h, yb, ipw, nw, opw, ww, wb, gw, gb, dw, dbp, bp, dout, part);
    hipLaunchKernelGGL(k_pen2, dim3(1), dim3(128), 0, stream, part, dout + 13*N_BL);
}

// Round 13
// 214.251 us; speedup vs baseline: 3.0770x; 3.0770x over previous
//
#include <hip/hip_runtime.h>
#include <math.h>

// ---------------- problem constants ----------------
#define Bn_   32
#define Ln_   8192
#define LCn   8184            // L - 8
#define NLn   2
#define NCHn  328             // scan chunks (328 % 4 == 0; 41*8 exact for scanC pipeline)
#define CHn   25              // chunk length (328*25 = 8200 >= 8184, tail guarded)
#define NGn   24              // sequence groups (96 seqs / 4 per wave)

static constexpr long N_BL = (long)Bn_ * LCn;            // 261888
static constexpr long NCAR = (long)NGn * NCHn * 256;     // 2,015,232 carry floats (< 8*N_BL)

// ---- ws layout (float offsets), total 48N = 50.28 MB ----
static constexpr long OFF_H    = 0;                  // 12N  (mamba hidden, layer-0 output)
static constexpr long OFF_REC  = 12*N_BL;            // 24N  (rec = [u0..3, lg0..3] per (m,b,t))
static constexpr long OFF_YB   = 36*N_BL;            // 12N  (scan y, [m][b][t][d]); Ap aliases first 8N
static constexpr long OFF_PART = OFF_REC;            // part aliases rec (dead after scanD l=1)
// d_out scratch: Sv [4N,12N)

#define L2E_  1.4426950408889634f     // log2(e)
#define LN2_  0.6931471805599453f     // ln(2)
#define EXP2_(x) __builtin_amdgcn_exp2f(x)
#define LOG2_(x) __builtin_amdgcn_logf(x)

__device__ __forceinline__ float si_(float v) {
    float e = EXP2_(-v * L2E_);
    return v * __builtin_amdgcn_rcpf(1.f + e);
}

__device__ __forceinline__ float sel4(float4 v, int d) {
    return (d & 2) ? ((d & 1) ? v.w : v.z) : ((d & 1) ? v.y : v.x);
}

__device__ __forceinline__ float rowsum16(float p) {
    p += __int_as_float(__builtin_amdgcn_update_dpp(0, __float_as_int(p), 0x128, 0xF, 0xF, true)); // row_ror:8
    p += __int_as_float(__builtin_amdgcn_update_dpp(0, __float_as_int(p), 0x124, 0xF, 0xF, true)); // row_ror:4
    p += __int_as_float(__builtin_amdgcn_update_dpp(0, __float_as_int(p), 0x122, 0xF, 0xF, true)); // row_ror:2
    p += __int_as_float(__builtin_amdgcn_update_dpp(0, __float_as_int(p), 0x121, 0xF, 0xF, true)); // row_ror:1
    return p;
}

// xin(p) = [z0, xd, z0_flip, xd_flip] recomputed from x (x is 1MB -> L2-hot)
__device__ __forceinline__ float4 compute_xin(const float* __restrict__ xb, int p) {
    const float c0 = 1.f/280.f, c1 = -4.f/105.f, c2 = 0.2f, c3 = -0.8f,
                c5 = 0.8f, c6 = -0.2f, c7 = 4.f/105.f, c8 = -1.f/280.f;
    float xd  = c0*xb[p]   + c1*xb[p+1] + c2*xb[p+2] + c3*xb[p+3]
              + c5*xb[p+5] + c6*xb[p+6] + c7*xb[p+7] + c8*xb[p+8];
    int tf = LCn - 1 - p;
    float xdf = c0*xb[tf]   + c1*xb[tf+1] + c2*xb[tf+2] + c3*xb[tf+3]
              + c5*xb[tf+5] + c6*xb[tf+6] + c7*xb[tf+7] + c8*xb[tf+8];
    float4 v; v.x = xb[p+4]; v.y = xd; v.z = xb[tf+4]; v.w = xdf;
    return v;
}

__device__ __forceinline__ float4 rms_xproj(float4 hv, const float* __restrict__ wn,
                                            const float* __restrict__ W) {
    float ms = (hv.x*hv.x + hv.y*hv.y + hv.z*hv.z + hv.w*hv.w)*0.25f + 1e-5f;
    float rs = __builtin_amdgcn_rsqf(ms);
    float hn0 = hv.x*rs*wn[0], hn1 = hv.y*rs*wn[1];
    float hn2 = hv.z*rs*wn[2], hn3 = hv.w*rs*wn[3];
    float4 o;
    o.x = W[0]*hn0  + W[1]*hn1  + W[2]*hn2  + W[3]*hn3;
    o.y = W[4]*hn0  + W[5]*hn1  + W[6]*hn2  + W[7]*hn3;
    o.z = W[8]*hn0  + W[9]*hn1  + W[10]*hn2 + W[11]*hn3;
    o.w = W[12]*hn0 + W[13]*hn1 + W[14]*hn2 + W[15]*hn3;
    return o;
}

__device__ __forceinline__ void conv_lg_store(const float4* xp, int k, int ml,
                                              const float* __restrict__ cw,
                                              const float* __restrict__ cbv,
                                              const float* __restrict__ xpw,
                                              const float* __restrict__ dtw,
                                              const float* __restrict__ dtb,
                                              float* __restrict__ rp) {
    const float* wc = cw  + ml*16;
    const float* bc = cbv + ml*4;
    float acc0 = bc[0], acc1 = bc[1], acc2 = bc[2], acc3 = bc[3];
#pragma unroll
    for (int j = 0; j < 4; j++) {
        float4 xv = xp[k + j];
        acc0 = fmaf(xv.x, wc[0*4+j], acc0);
        acc1 = fmaf(xv.y, wc[1*4+j], acc1);
        acc2 = fmaf(xv.z, wc[2*4+j], acc2);
        acc3 = fmaf(xv.w, wc[3*4+j], acc3);
    }
    float4 o;
    o.x = si_(acc0); o.y = si_(acc1); o.z = si_(acc2); o.w = si_(acc3);
    const float* P = xpw + (long)ml*33*4;
    float dtr = o.x*P[0] + o.y*P[1] + o.z*P[2] + o.w*P[3];
    const float* dwv = dtw + ml*4;
    const float* dbv = dtb + ml*4;
    float4 lg;
    lg.x = LOG2_(1.f + EXP2_(fmaf(dtr, dwv[0], dbv[0]) * L2E_));
    lg.y = LOG2_(1.f + EXP2_(fmaf(dtr, dwv[1], dbv[1]) * L2E_));
    lg.z = LOG2_(1.f + EXP2_(fmaf(dtr, dwv[2], dbv[2]) * L2E_));
    lg.w = LOG2_(1.f + EXP2_(fmaf(dtr, dwv[3], dbv[3]) * L2E_));
    *(float4*)rp       = o;
    *(float4*)(rp + 4) = lg;
}

// ---------------- 1. fused deriv + rmsnorm0 + in_proj0 + conv0 + silu + lg ----------------
__global__ __launch_bounds__(256)
void k_pre0(const float* __restrict__ x,
            const float* __restrict__ ipw, const float* __restrict__ cw,
            const float* __restrict__ cbv, const float* __restrict__ nw,
            const float* __restrict__ xpw, const float* __restrict__ dtw,
            const float* __restrict__ dtb, float* __restrict__ rec) {
    __shared__ float4 xp[259];
    int blk = blockIdx.x;
    int m = blk >> 10, bb = (blk >> 5) & 31, tile = blk & 31;
    int ml = m*NLn;                 // l = 0
    int t0 = tile << 8, k = threadIdx.x;
    int t  = t0 + k;
    const float* xb = x + (long)bb*Ln_;
    const float* W  = ipw + (long)ml*32;
    const float* wn = nw  + ml*4;
    auto G = [&](int p) -> float4 {
        float4 o; o.x = o.y = o.z = o.w = 0.f;
        if (p >= 0 && p < LCn) o = rms_xproj(compute_xin(xb, p), wn, W);
        return o;
    };
    xp[k + 3] = G(t);
    if (k < 3) xp[k] = G(t0 + k - 3);
    __syncthreads();
    if (t >= LCn) return;
    conv_lg_store(xp, k, ml, cw, cbv, xpw, dtw, dtb,
                  rec + ((long)m*N_BL + (long)bb*LCn + t)*8);
}

// ---------------- 2. fused post0 (writes h) + rmsnorm1 + in_proj1 + conv1 + silu + lg ----------------
__global__ __launch_bounds__(256)
void k_mid(const float* __restrict__ x, const float* __restrict__ yb,
           float* __restrict__ hout,
           const float* __restrict__ ipw, const float* __restrict__ cw,
           const float* __restrict__ cbv, const float* __restrict__ nw,
           const float* __restrict__ xpw, const float* __restrict__ dtw,
           const float* __restrict__ dtb, const float* __restrict__ opw,
           float* __restrict__ rec) {
    __shared__ float4 xp[259];
    int blk = blockIdx.x;
    int m = blk >> 10, bb = (blk >> 5) & 31, tile = blk & 31;
    int ml0 = m*NLn, ml1 = ml0 + 1;
    int t0 = tile << 8, k = threadIdx.x;
    int t  = t0 + k;
    const float* xb  = x + (long)bb*Ln_;
    const float* wn0 = nw + ml0*4;
    const float* Wr  = ipw + (long)(ml0*8 + 4)*4;
    const float* O   = opw + ml0*16;
    const float* wn1 = nw + ml1*4;
    const float* W1  = ipw + (long)ml1*32;
    auto H = [&](int p) -> float4 {
        float4 hv = compute_xin(xb, p);
        float ms = (hv.x*hv.x + hv.y*hv.y + hv.z*hv.z + hv.w*hv.w)*0.25f + 1e-5f;
        float rs = __builtin_amdgcn_rsqf(ms);
        float hn0 = hv.x*rs*wn0[0], hn1 = hv.y*rs*wn0[1];
        float hn2 = hv.z*rs*wn0[2], hn3 = hv.w*rs*wn0[3];
        float4 yv = *(const float4*)(yb + ((long)m*N_BL + (long)bb*LCn + p)*4);
        float g0 = yv.x * si_(Wr[0]*hn0  + Wr[1]*hn1  + Wr[2]*hn2  + Wr[3]*hn3);
        float g1 = yv.y * si_(Wr[4]*hn0  + Wr[5]*hn1  + Wr[6]*hn2  + Wr[7]*hn3);
        float g2 = yv.z * si_(Wr[8]*hn0  + Wr[9]*hn1  + Wr[10]*hn2 + Wr[11]*hn3);
        float g3 = yv.w * si_(Wr[12]*hn0 + Wr[13]*hn1 + Wr[14]*hn2 + Wr[15]*hn3);
        float4 o;
        o.x = O[0]*g0  + O[1]*g1  + O[2]*g2  + O[3]*g3  + hv.x;
        o.y = O[4]*g0  + O[5]*g1  + O[6]*g2  + O[7]*g3  + hv.y;
        o.z = O[8]*g0  + O[9]*g1  + O[10]*g2 + O[11]*g3 + hv.z;
        o.w = O[12]*g0 + O[13]*g1 + O[14]*g2 + O[15]*g3 + hv.w;
        return o;
    };
    float4 zf; zf.x = zf.y = zf.z = zf.w = 0.f;
    if (t < LCn) {
        float4 hnew = H(t);
        *(float4*)(hout + ((long)m*N_BL + (long)bb*LCn + t)*4) = hnew;
        xp[k + 3] = rms_xproj(hnew, wn1, W1);
    } else {
        xp[k + 3] = zf;
    }
    if (k < 3) {
        int p = t0 + k - 3;
        xp[k] = (p >= 0) ? rms_xproj(H(p), wn1, W1) : zf;
    }
    __syncthreads();
    if (t >= LCn) return;
    conv_lg_store(xp, k, ml1, cw, cbv, xpw, dtw, dtb,
                  rec + ((long)m*N_BL + (long)bb*LCn + t)*8);
}

// ---------------- 3a. scan phase B: per-chunk carries ----------------
__global__ __launch_bounds__(256, 8)
void k_scanB(const float* __restrict__ rec, int l,
             const float* __restrict__ xpw, const float* __restrict__ Alog,
             float* __restrict__ Ap, float* __restrict__ Sv) {
    int wid  = blockIdx.x*4 + (threadIdx.x >> 6);
    int lane = threadIdx.x & 63;
    int chunk = wid % NCHn;
    int g     = wid / NCHn;         // 0..23
    int m = g >> 3;
    int s = lane >> 4, n = lane & 15;
    int bb = (g & 7)*4 + s;
    int ml = m*NLn + l;
    const float* P  = xpw + (long)ml*33*4;
    const float* PB = P + (1+n)*4;
    float pb0 = PB[0]*LN2_, pb1 = PB[1]*LN2_, pb2 = PB[2]*LN2_, pb3 = PB[3]*LN2_;
    const float* AL = Alog + (long)ml*64 + n;
    float4 Av;
    Av.x = -EXP2_(AL[0]  * L2E_);
    Av.y = -EXP2_(AL[16] * L2E_);
    Av.z = -EXP2_(AL[32] * L2E_);
    Av.w = -EXP2_(AL[48] * L2E_);
    const float* rb = rec + ((long)m*N_BL + (long)bb*LCn)*8;
    int t0 = chunk*CHn, t1 = min(t0 + CHn, LCn);
    float4 ap; ap.x = ap.y = ap.z = ap.w = 1.f;
    float4 sv; sv.x = sv.y = sv.z = sv.w = 0.f;
#pragma unroll 4
    for (int t = t0; t < t1; t++) {
        float4 u  = *(const float4*)(rb + (long)t*8);
        float4 lg = *(const float4*)(rb + (long)t*8 + 4);
        float Bv = u.x*pb0 + u.y*pb1 + u.z*pb2 + u.w*pb3;
        float4 a;
        a.x = EXP2_(lg.x * Av.x); a.y = EXP2_(lg.y * Av.y);
        a.z = EXP2_(lg.z * Av.z); a.w = EXP2_(lg.w * Av.w);
        sv.x = fmaf(a.x, sv.x, lg.x*u.x*Bv);
        sv.y = fmaf(a.y, sv.y, lg.y*u.y*Bv);
        sv.z = fmaf(a.z, sv.z, lg.z*u.z*Bv);
        sv.w = fmaf(a.w, sv.w, lg.w*u.w*Bv);
        ap.x *= a.x; ap.y *= a.y; ap.z *= a.z; ap.w *= a.w;
    }
    long ci = (((long)g*NCHn + chunk)*64 + lane)*4;
    *(float4*)(Ap + ci) = ap;
    *(float4*)(Sv + ci) = sv;
}

// ---------------- 3b. scan phase C (pipelined exclusive prefix) ----------------
#define SCANC_G 8
__global__ __launch_bounds__(256)
void k_scanC(const float* __restrict__ Ap, float* __restrict__ Sv) {
    int g   = blockIdx.x;           // 24 groups
    int tid = threadIdx.x;          // 256 states per group
    long base = (long)g*NCHn*256 + tid;
    const int NFULL = NCHn / SCANC_G;        // 41, exact (328 = 41*8)
    float h = 0.f;
    float ca[SCANC_G], cs[SCANC_G], na[SCANC_G], ns[SCANC_G];
#pragma unroll
    for (int j = 0; j < SCANC_G; j++) {
        ca[j] = Ap[base + (long)j*256];
        cs[j] = Sv[base + (long)j*256];
    }
    for (int grp = 0; grp < NFULL; grp++) {
        long gb = base + (long)grp*SCANC_G*256;
        if (grp + 1 < NFULL) {
            long nb = gb + (long)SCANC_G*256;
#pragma unroll
            for (int j = 0; j < SCANC_G; j++) {
                na[j] = Ap[nb + (long)j*256];
                ns[j] = Sv[nb + (long)j*256];
            }
        }
#pragma unroll
        for (int j = 0; j < SCANC_G; j++) {
            Sv[gb + (long)j*256] = h;            // exclusive prefix: h0 for chunk
            h = fmaf(ca[j], h, cs[j]);
        }
#pragma unroll
        for (int j = 0; j < SCANC_G; j++) { ca[j] = na[j]; cs[j] = ns[j]; }
    }
}

// ---------------- 3c. scan phase D: final scan + y (D-term folded) ----------------
__global__ __launch_bounds__(256, 8)
void k_scanD(const float* __restrict__ rec, float* __restrict__ yb, int l,
             const float* __restrict__ xpw, const float* __restrict__ Alog,
             const float* __restrict__ H0, const float* __restrict__ Dp) {
    int wid  = blockIdx.x*4 + (threadIdx.x >> 6);
    int lane = threadIdx.x & 63;
    int chunk = wid % NCHn;
    int g     = wid / NCHn;
    int m = g >> 3;
    int s = lane >> 4, n = lane & 15;
    int bb = (g & 7)*4 + s;
    int ml = m*NLn + l;
    const float* P  = xpw + (long)ml*33*4;
    const float* PB = P + (1+n)*4;
    float pb0 = PB[0]*LN2_, pb1 = PB[1]*LN2_, pb2 = PB[2]*LN2_, pb3 = PB[3]*LN2_;
    const float* PC = P + (17+n)*4;
    float pc0 = PC[0], pc1 = PC[1], pc2 = PC[2], pc3 = PC[3];
    const float* AL = Alog + (long)ml*64 + n;
    float4 Av;
    Av.x = -EXP2_(AL[0]  * L2E_);
    Av.y = -EXP2_(AL[16] * L2E_);
    Av.z = -EXP2_(AL[32] * L2E_);
    Av.w = -EXP2_(AL[48] * L2E_);
    float Dd = Dp[ml*4 + (n & 3)];
    float4 h = *(const float4*)(H0 + (((long)g*NCHn + chunk)*64 + lane)*4);
    const float* rb = rec + ((long)m*N_BL + (long)bb*LCn)*8;
    float* ym = yb + ((long)m*N_BL + (long)bb*LCn)*4;   // [m][b][t][d]
    int t0 = chunk*CHn, t1 = min(t0 + CHn, LCn);
#pragma unroll 4
    for (int t = t0; t < t1; t++) {
        float4 u  = *(const float4*)(rb + (long)t*8);
        float4 lg = *(const float4*)(rb + (long)t*8 + 4);
        float Bv = u.x*pb0 + u.y*pb1 + u.z*pb2 + u.w*pb3;
        float Cv = u.x*pc0 + u.y*pc1 + u.z*pc2 + u.w*pc3;
        float4 a;
        a.x = EXP2_(lg.x * Av.x); a.y = EXP2_(lg.y * Av.y);
        a.z = EXP2_(lg.z * Av.z); a.w = EXP2_(lg.w * Av.w);
        h.x = fmaf(a.x, h.x, lg.x*u.x*Bv);
        h.y = fmaf(a.y, h.y, lg.y*u.y*Bv);
        h.z = fmaf(a.z, h.z, lg.z*u.z*Bv);
        h.w = fmaf(a.w, h.w, lg.w*u.w*Bv);
        float px = rowsum16(h.x * Cv);
        float py = rowsum16(h.y * Cv);
        float pz = rowsum16(h.z * Cv);
        float pw = rowsum16(h.w * Cv);
        if (n < 4) {
            float out = (n & 2) ? ((n & 1) ? pw : pz) : ((n & 1) ? py : px);
            float ud  = sel4(u, n);
            ym[(long)t*4 + n] = fmaf(ud, Dd, out);
        }
    }
}

// ---------------- 4. fused tail: post1+head (raw in LDS) + smooth + yhat + pen partials ----------------
__global__ __launch_bounds__(256)
void k_tail(const float* __restrict__ x, const float* __restrict__ hin,
            const float* __restrict__ yb,
            const float* __restrict__ ipw, const float* __restrict__ nw,
            const float* __restrict__ opw,
            const float* __restrict__ ww, const float* __restrict__ wb,
            const float* __restrict__ gw, const float* __restrict__ gb,
            const float* __restrict__ dw, const float* __restrict__ dbp,
            const float* __restrict__ bp,
            float* __restrict__ dout, double* __restrict__ part) {
    int b    = blockIdx.x >> 5;     // 32 b
    int tile = blockIdx.x & 31;     // 32 tiles of 256
    int k    = threadIdx.x;
    int t0   = tile << 8;
    __shared__ float ro_[266], rg_[266], rd_[266];   // raw for t in [t0-4, t0+262)
    __shared__ float so_[257], sg_[257], sd_[257];
    auto rawcalc = [&](int e) {
        int t = t0 - 4 + e;
        float vo = 0.f, vg = 0.f, vd = 0.f;
        if (t >= 0 && t < LCn) {
            long r = (long)b*LCn + t;
            float4 om[3];
#pragma unroll
            for (int m = 0; m < 3; m++) {
                int ml = m*NLn + 1;
                float4 hv = *(const float4*)(hin + (long)m*4*N_BL + r*4);
                float ms = (hv.x*hv.x + hv.y*hv.y + hv.z*hv.z + hv.w*hv.w)*0.25f + 1e-5f;
                float rs = __builtin_amdgcn_rsqf(ms);
                const float* wn = nw + ml*4;
                float hn0 = hv.x*rs*wn[0], hn1 = hv.y*rs*wn[1];
                float hn2 = hv.z*rs*wn[2], hn3 = hv.w*rs*wn[3];
                const float* W = ipw + (long)(ml*8 + 4)*4;
                float4 yv = *(const float4*)(yb + ((long)m*N_BL + r)*4);
                float g0 = yv.x * si_(W[0]*hn0  + W[1]*hn1  + W[2]*hn2  + W[3]*hn3);
                float g1 = yv.y * si_(W[4]*hn0  + W[5]*hn1  + W[6]*hn2  + W[7]*hn3);
                float g2 = yv.z * si_(W[8]*hn0  + W[9]*hn1  + W[10]*hn2 + W[11]*hn3);
                float g3 = yv.w * si_(W[12]*hn0 + W[13]*hn1 + W[14]*hn2 + W[15]*hn3);
                const float* O = opw + ml*16;
                float4 o;
                o.x = O[0]*g0  + O[1]*g1  + O[2]*g2  + O[3]*g3  + hv.x;
                o.y = O[4]*g0  + O[5]*g1  + O[6]*g2  + O[7]*g3  + hv.y;
                o.z = O[8]*g0  + O[9]*g1  + O[10]*g2 + O[11]*g3 + hv.z;
                o.w = O[12]*g0 + O[13]*g1 + O[14]*g2 + O[15]*g3 + hv.w;
                om[m] = o;
            }
            float4* c = (float4*)(dout + N_BL + r*12);   // halo double-writes are identical
            c[0] = om[0]; c[1] = om[1]; c[2] = om[2];
            vo = om[0].x*ww[0] + om[0].y*ww[1] + om[0].z*ww[2] + om[0].w*ww[3] + wb[0];
            vg = (om[1].x*gw[0] + om[1].y*gw[1] + om[1].z*gw[2] + om[1].w*gw[3] + gb[0]) / 1000.0f;
            vd = fmaxf(om[2].x*dw[0] + om[2].y*dw[1] + om[2].z*dw[2] + om[2].w*dw[3] + dbp[0], 0.f);
        }
        ro_[e] = vo; rg_[e] = vg; rd_[e] = vd;
    };
    rawcalc(k);
    if (k < 10) rawcalc(k + 256);
    __syncthreads();
    auto smo = [&](int kk, float& o, float& g, float& d) {
        o = g = d = 0.f;
#pragma unroll
        for (int j = 0; j < 10; j++) {
            o += fabsf(ro_[kk + j]); g += rg_[kk + j]; d += fabsf(rd_[kk + j]);
        }
        o *= 0.1f; g *= 0.1f; d *= 0.1f;
    };
    float so, sg, sd;
    smo(k, so, sg, sd);
    so_[k] = so; sg_[k] = sg; sd_[k] = sd;
    if (k == 0) {
        float a1, b1, c1;
        smo(256, a1, b1, c1);
        so_[256] = a1; sg_[256] = b1; sd_[256] = c1;
    }
    __syncthreads();
    int t = t0 + k;
    if (t < LCn) {
        const float* xb = x + (long)b * Ln_;
        const float c0 = 1.f/280.f, c1 = -4.f/105.f, c2 = 0.2f, c3 = -0.8f,
                    c5 = 0.8f, c6 = -0.2f, c7 = 4.f/105.f, c8 = -1.f/280.f;
        float xd  = c0*xb[t]   + c1*xb[t+1] + c2*xb[t+2] + c3*xb[t+3]
                  + c5*xb[t+5] + c6*xb[t+6] + c7*xb[t+7] + c8*xb[t+8];
        float z1 = xb[t+4];
        float z2 = xd / 0.0001f;
        float bq = fmaxf(bp[0], 0.f) / 1000.0f;
        dout[(long)b*LCn + t] = -so*so*z1 + sg*z2 - bq*z1*z1*z2 - sd;
    }
    double v[6] = {0,0,0,0,0,0};
    if (t >= 1 && t <= LCn - 2) {
        double go = (double)so_[k+1] - (double)so_[k];
        double gg = (double)sg_[k+1] - (double)sg_[k];
        double gd = (double)sd_[k+1] - (double)sd_[k];
        v[0] = go; v[1] = go*go;
        v[2] = gg; v[3] = gg*gg;
        v[4] = gd; v[5] = gd*gd;
    }
#pragma unroll
    for (int j = 0; j < 6; j++) {
        for (int off = 32; off > 0; off >>= 1)
            v[j] += __shfl_down(v[j], off, 64);
    }
    __shared__ double wsum[4][6];
    int w = threadIdx.x >> 6;
    if ((threadIdx.x & 63) == 0) {
#pragma unroll
        for (int j = 0; j < 6; j++) wsum[w][j] = v[j];
    }
    __syncthreads();
    if (threadIdx.x == 0) {
        double sarr[6];
#pragma unroll
        for (int j = 0; j < 6; j++)
            sarr[j] = wsum[0][j] + wsum[1][j] + wsum[2][j] + wsum[3][j];
        long pb = (((long)0*32 + b)*32 + tile)*2;
        part[pb]   = sarr[0]; part[pb+1] = sarr[1];
        pb = (((long)1*32 + b)*32 + tile)*2;
        part[pb]   = sarr[2]; part[pb+1] = sarr[3];
        pb = (((long)2*32 + b)*32 + tile)*2;
        part[pb]   = sarr[4]; part[pb+1] = sarr[5];
    }
}

// ---------------- 5. penalty finalize ----------------
__global__ void k_pen2(const double* __restrict__ part, float* __restrict__ pout) {
    int tid = threadIdx.x;          // 128 threads, 96 active
    double var = 0.0;
    if (tid < 96) {
        int which = tid / 32, b = tid % 32;
        double su = 0.0, s2 = 0.0;
        for (int tl = 0; tl < 32; tl++) {
            const double* p = part + (((long)which*32 + b)*32 + tl)*2;
            su += p[0]; s2 += p[1];
        }
        const double N = (double)(LCn - 2);
        var = (s2 - su*su/N) / (N - 1.0);
    }
    __shared__ double sh[128];
    sh[tid] = var;
    __syncthreads();
    for (int o = 64; o > 0; o >>= 1) {
        if (tid < o) sh[tid] += sh[tid + o];
        __syncthreads();
    }
    if (tid == 0) pout[0] = (float)(sh[0] / 96.0);
}

// ---------------- launch ----------------
extern "C" void kernel_launch(void* const* d_in, const int* in_sizes, int n_in,
                              void* d_out, int out_size, void* d_ws, size_t ws_size,
                              hipStream_t stream) {
    const float* x    = (const float*)d_in[0];
    const float* ipw  = (const float*)d_in[1];
    const float* cw   = (const float*)d_in[2];
    const float* cbv  = (const float*)d_in[3];
    const float* xpw  = (const float*)d_in[4];
    const float* dtw  = (const float*)d_in[5];
    const float* dtb  = (const float*)d_in[6];
    const float* Alog = (const float*)d_in[7];
    const float* Dp   = (const float*)d_in[8];
    const float* nw   = (const float*)d_in[9];
    const float* opw  = (const float*)d_in[10];
    const float* ww   = (const float*)d_in[11];
    const float* wb   = (const float*)d_in[12];
    const float* gw   = (const float*)d_in[13];
    const float* gb   = (const float*)d_in[14];
    const float* dw   = (const float*)d_in[15];
    const float* dbp  = (const float*)d_in[16];
    const float* bp   = (const float*)d_in[17];

    float* ws   = (float*)d_ws;
    float* h    = ws + OFF_H;
    float* rec  = ws + OFF_REC;
    float* yb   = ws + OFF_YB;
    float* ap   = yb;                 // Ap aliases YB[0,8N) (dead before scanD writes y)
    double* part = (double*)(ws + OFF_PART);   // aliases rec (dead after scanD l=1)
    float* dout = (float*)d_out;
    float* sv   = dout + 4*N_BL;      // d_out scratch (8N region), last read by scanD l=1

    hipLaunchKernelGGL(k_pre0, dim3(3072), dim3(256), 0, stream,
                       x, ipw, cw, cbv, nw, xpw, dtw, dtb, rec);
    hipLaunchKernelGGL(k_scanB, dim3(NGn*NCHn/4), dim3(256), 0, stream,
                       rec, 0, xpw, Alog, ap, sv);
    hipLaunchKernelGGL(k_scanC, dim3(NGn), dim3(256), 0, stream, ap, sv);
    hipLaunchKernelGGL(k_scanD, dim3(NGn*NCHn/4), dim3(256), 0, stream,
                       rec, yb, 0, xpw, Alog, sv, Dp);
    hipLaunchKernelGGL(k_mid, dim3(3072), dim3(256), 0, stream,
                       x, yb, h, ipw, cw, cbv, nw, xpw, dtw, dtb, opw, rec);
    hipLaunchKernelGGL(k_scanB, dim3(NGn*NCHn/4), dim3(256), 0, stream,
                       rec, 1, xpw, Alog, ap, sv);
    hipLaunchKernelGGL(k_scanC, dim3(NGn), dim3(256), 0, stream, ap, sv);
    hipLaunchKernelGGL(k_scanD, dim3(NGn*NCHn/4), dim3(256), 0, stream,
                       rec, yb, 1, xpw, Alog, sv, Dp);
    hipLaunchKernelGGL(k_tail, dim3(1024), dim3(256), 0, stream,
                       x, h, yb, ipw, nw, opw, ww, wb, gw, gb, dw, dbp, bp, dout, part);
    hipLaunchKernelGGL(k_pen2, dim3(1), dim3(128), 0, stream, part, dout + 13*N_BL);
}

// Round 14
// 177.786 us; speedup vs baseline: 3.7081x; 1.2051x over previous
//
#include <hip/hip_runtime.h>
#include <math.h>

// ---------------- problem constants ----------------
#define Bn_   32
#define Ln_   8192
#define LCn   8184            // L - 8
#define NLn   2
#define NCHn  341             // scan chunks (341*24 = 8184 exactly, no tail)
#define CHn   24              // chunk length
#define NGn   24              // sequence groups (96 seqs / 4 per wave)

static constexpr long N_BL = (long)Bn_ * LCn;            // 261888

// ---- ws layout (float offsets), total 48N = 50.28 MB ----
static constexpr long OFF_H    = 0;                  // 12N  (mamba hidden, layer-0 output)
static constexpr long OFF_REC  = 12*N_BL;            // 24N  (rec = [u0..3, lg0..3] per (m,b,t))
static constexpr long OFF_YB   = 36*N_BL;            // 12N  (scan y, [m][b][t][d]); Ap aliases first 8N
// aliases over REC (dead after postHead):
static constexpr long OFF_RAW  = OFF_REC;            // 3N
static constexpr long OFF_PART = OFF_REC + 3*N_BL;   // 6144 doubles
// d_out scratch: Sv [4N,12N)  (out_size = 13N+1)

#define L2E_  1.4426950408889634f     // log2(e)
#define LN2_  0.6931471805599453f     // ln(2)
#define EXP2_(x) __builtin_amdgcn_exp2f(x)
#define LOG2_(x) __builtin_amdgcn_logf(x)

__device__ __forceinline__ float si_(float v) {
    float e = EXP2_(-v * L2E_);
    return v * __builtin_amdgcn_rcpf(1.f + e);
}

__device__ __forceinline__ float sel4(float4 v, int d) {
    return (d & 2) ? ((d & 1) ? v.w : v.z) : ((d & 1) ? v.y : v.x);
}

__device__ __forceinline__ float rowsum16(float p) {
    p += __int_as_float(__builtin_amdgcn_update_dpp(0, __float_as_int(p), 0x128, 0xF, 0xF, true)); // row_ror:8
    p += __int_as_float(__builtin_amdgcn_update_dpp(0, __float_as_int(p), 0x124, 0xF, 0xF, true)); // row_ror:4
    p += __int_as_float(__builtin_amdgcn_update_dpp(0, __float_as_int(p), 0x122, 0xF, 0xF, true)); // row_ror:2
    p += __int_as_float(__builtin_amdgcn_update_dpp(0, __float_as_int(p), 0x121, 0xF, 0xF, true)); // row_ror:1
    return p;
}

// xin(p) = [z0, xd, z0_flip, xd_flip] recomputed from x (x is 1MB -> L2-hot)
__device__ __forceinline__ float4 compute_xin(const float* __restrict__ xb, int p) {
    const float c0 = 1.f/280.f, c1 = -4.f/105.f, c2 = 0.2f, c3 = -0.8f,
                c5 = 0.8f, c6 = -0.2f, c7 = 4.f/105.f, c8 = -1.f/280.f;
    float xd  = c0*xb[p]   + c1*xb[p+1] + c2*xb[p+2] + c3*xb[p+3]
              + c5*xb[p+5] + c6*xb[p+6] + c7*xb[p+7] + c8*xb[p+8];
    int tf = LCn - 1 - p;
    float xdf = c0*xb[tf]   + c1*xb[tf+1] + c2*xb[tf+2] + c3*xb[tf+3]
              + c5*xb[tf+5] + c6*xb[tf+6] + c7*xb[tf+7] + c8*xb[tf+8];
    float4 v; v.x = xb[p+4]; v.y = xd; v.z = xb[tf+4]; v.w = xdf;
    return v;
}

__device__ __forceinline__ float4 rms_xproj(float4 hv, const float* __restrict__ wn,
                                            const float* __restrict__ W) {
    float ms = (hv.x*hv.x + hv.y*hv.y + hv.z*hv.z + hv.w*hv.w)*0.25f + 1e-5f;
    float rs = __builtin_amdgcn_rsqf(ms);
    float hn0 = hv.x*rs*wn[0], hn1 = hv.y*rs*wn[1];
    float hn2 = hv.z*rs*wn[2], hn3 = hv.w*rs*wn[3];
    float4 o;
    o.x = W[0]*hn0  + W[1]*hn1  + W[2]*hn2  + W[3]*hn3;
    o.y = W[4]*hn0  + W[5]*hn1  + W[6]*hn2  + W[7]*hn3;
    o.z = W[8]*hn0  + W[9]*hn1  + W[10]*hn2 + W[11]*hn3;
    o.w = W[12]*hn0 + W[13]*hn1 + W[14]*hn2 + W[15]*hn3;
    return o;
}

__device__ __forceinline__ void conv_lg_store(const float4* xp, int k, int ml,
                                              const float* __restrict__ cw,
                                              const float* __restrict__ cbv,
                                              const float* __restrict__ xpw,
                                              const float* __restrict__ dtw,
                                              const float* __restrict__ dtb,
                                              float* __restrict__ rp) {
    const float* wc = cw  + ml*16;
    const float* bc = cbv + ml*4;
    float acc0 = bc[0], acc1 = bc[1], acc2 = bc[2], acc3 = bc[3];
#pragma unroll
    for (int j = 0; j < 4; j++) {
        float4 xv = xp[k + j];
        acc0 = fmaf(xv.x, wc[0*4+j], acc0);
        acc1 = fmaf(xv.y, wc[1*4+j], acc1);
        acc2 = fmaf(xv.z, wc[2*4+j], acc2);
        acc3 = fmaf(xv.w, wc[3*4+j], acc3);
    }
    float4 o;
    o.x = si_(acc0); o.y = si_(acc1); o.z = si_(acc2); o.w = si_(acc3);
    const float* P = xpw + (long)ml*33*4;
    float dtr = o.x*P[0] + o.y*P[1] + o.z*P[2] + o.w*P[3];
    const float* dwv = dtw + ml*4;
    const float* dbv = dtb + ml*4;
    float4 lg;
    lg.x = LOG2_(1.f + EXP2_(fmaf(dtr, dwv[0], dbv[0]) * L2E_));
    lg.y = LOG2_(1.f + EXP2_(fmaf(dtr, dwv[1], dbv[1]) * L2E_));
    lg.z = LOG2_(1.f + EXP2_(fmaf(dtr, dwv[2], dbv[2]) * L2E_));
    lg.w = LOG2_(1.f + EXP2_(fmaf(dtr, dwv[3], dbv[3]) * L2E_));
    *(float4*)rp       = o;
    *(float4*)(rp + 4) = lg;
}

// ---------------- 1. fused deriv + rmsnorm0 + in_proj0 + conv0 + silu + lg ----------------
__global__ __launch_bounds__(256)
void k_pre0(const float* __restrict__ x,
            const float* __restrict__ ipw, const float* __restrict__ cw,
            const float* __restrict__ cbv, const float* __restrict__ nw,
            const float* __restrict__ xpw, const float* __restrict__ dtw,
            const float* __restrict__ dtb, float* __restrict__ rec) {
    __shared__ float4 xp[259];
    int blk = blockIdx.x;
    int m = blk >> 10, bb = (blk >> 5) & 31, tile = blk & 31;
    int ml = m*NLn;                 // l = 0
    int t0 = tile << 8, k = threadIdx.x;
    int t  = t0 + k;
    const float* xb = x + (long)bb*Ln_;
    const float* W  = ipw + (long)ml*32;
    const float* wn = nw  + ml*4;
    auto G = [&](int p) -> float4 {
        float4 o; o.x = o.y = o.z = o.w = 0.f;
        if (p >= 0 && p < LCn) o = rms_xproj(compute_xin(xb, p), wn, W);
        return o;
    };
    xp[k + 3] = G(t);
    if (k < 3) xp[k] = G(t0 + k - 3);
    __syncthreads();
    if (t >= LCn) return;
    conv_lg_store(xp, k, ml, cw, cbv, xpw, dtw, dtb,
                  rec + ((long)m*N_BL + (long)bb*LCn + t)*8);
}

// ---------------- 2. fused post0 (writes h) + rmsnorm1 + in_proj1 + conv1 + silu + lg ----------------
__global__ __launch_bounds__(256)
void k_mid(const float* __restrict__ x, const float* __restrict__ yb,
           float* __restrict__ hout,
           const float* __restrict__ ipw, const float* __restrict__ cw,
           const float* __restrict__ cbv, const float* __restrict__ nw,
           const float* __restrict__ xpw, const float* __restrict__ dtw,
           const float* __restrict__ dtb, const float* __restrict__ opw,
           float* __restrict__ rec) {
    __shared__ float4 xp[259];
    int blk = blockIdx.x;
    int m = blk >> 10, bb = (blk >> 5) & 31, tile = blk & 31;
    int ml0 = m*NLn, ml1 = ml0 + 1;
    int t0 = tile << 8, k = threadIdx.x;
    int t  = t0 + k;
    const float* xb  = x + (long)bb*Ln_;
    const float* wn0 = nw + ml0*4;
    const float* Wr  = ipw + (long)(ml0*8 + 4)*4;
    const float* O   = opw + ml0*16;
    const float* wn1 = nw + ml1*4;
    const float* W1  = ipw + (long)ml1*32;
    auto H = [&](int p) -> float4 {
        float4 hv = compute_xin(xb, p);
        float ms = (hv.x*hv.x + hv.y*hv.y + hv.z*hv.z + hv.w*hv.w)*0.25f + 1e-5f;
        float rs = __builtin_amdgcn_rsqf(ms);
        float hn0 = hv.x*rs*wn0[0], hn1 = hv.y*rs*wn0[1];
        float hn2 = hv.z*rs*wn0[2], hn3 = hv.w*rs*wn0[3];
        float4 yv = *(const float4*)(yb + ((long)m*N_BL + (long)bb*LCn + p)*4);
        float g0 = yv.x * si_(Wr[0]*hn0  + Wr[1]*hn1  + Wr[2]*hn2  + Wr[3]*hn3);
        float g1 = yv.y * si_(Wr[4]*hn0  + Wr[5]*hn1  + Wr[6]*hn2  + Wr[7]*hn3);
        float g2 = yv.z * si_(Wr[8]*hn0  + Wr[9]*hn1  + Wr[10]*hn2 + Wr[11]*hn3);
        float g3 = yv.w * si_(Wr[12]*hn0 + Wr[13]*hn1 + Wr[14]*hn2 + Wr[15]*hn3);
        float4 o;
        o.x = O[0]*g0  + O[1]*g1  + O[2]*g2  + O[3]*g3  + hv.x;
        o.y = O[4]*g0  + O[5]*g1  + O[6]*g2  + O[7]*g3  + hv.y;
        o.z = O[8]*g0  + O[9]*g1  + O[10]*g2 + O[11]*g3 + hv.z;
        o.w = O[12]*g0 + O[13]*g1 + O[14]*g2 + O[15]*g3 + hv.w;
        return o;
    };
    float4 zf; zf.x = zf.y = zf.z = zf.w = 0.f;
    if (t < LCn) {
        float4 hnew = H(t);
        *(float4*)(hout + ((long)m*N_BL + (long)bb*LCn + t)*4) = hnew;
        xp[k + 3] = rms_xproj(hnew, wn1, W1);
    } else {
        xp[k + 3] = zf;
    }
    if (k < 3) {
        int p = t0 + k - 3;
        xp[k] = (p >= 0) ? rms_xproj(H(p), wn1, W1) : zf;
    }
    __syncthreads();
    if (t >= LCn) return;
    conv_lg_store(xp, k, ml1, cw, cbv, xpw, dtw, dtb,
                  rec + ((long)m*N_BL + (long)bb*LCn + t)*8);
}

// ---------------- 3a. scan phase B ----------------
__global__ __launch_bounds__(256, 8)
void k_scanB(const float* __restrict__ rec, int l,
             const float* __restrict__ xpw, const float* __restrict__ Alog,
             float* __restrict__ Ap, float* __restrict__ Sv) {
    int wid  = blockIdx.x*4 + (threadIdx.x >> 6);
    int lane = threadIdx.x & 63;
    int chunk = wid % NCHn;
    int g     = wid / NCHn;         // 0..23
    int m = g >> 3;
    int s = lane >> 4, n = lane & 15;
    int bb = (g & 7)*4 + s;
    int ml = m*NLn + l;
    const float* P  = xpw + (long)ml*33*4;
    const float* PB = P + (1+n)*4;
    float pb0 = PB[0]*LN2_, pb1 = PB[1]*LN2_, pb2 = PB[2]*LN2_, pb3 = PB[3]*LN2_;
    const float* AL = Alog + (long)ml*64 + n;
    float4 Av;
    Av.x = -EXP2_(AL[0]  * L2E_);
    Av.y = -EXP2_(AL[16] * L2E_);
    Av.z = -EXP2_(AL[32] * L2E_);
    Av.w = -EXP2_(AL[48] * L2E_);
    const float* rb = rec + ((long)m*N_BL + (long)bb*LCn)*8;
    int t0 = chunk*CHn;
    float4 ap; ap.x = ap.y = ap.z = ap.w = 1.f;
    float4 sv; sv.x = sv.y = sv.z = sv.w = 0.f;
#pragma unroll 4
    for (int t = t0; t < t0 + CHn; t++) {
        float4 u  = *(const float4*)(rb + (long)t*8);
        float4 lg = *(const float4*)(rb + (long)t*8 + 4);
        float Bv = u.x*pb0 + u.y*pb1 + u.z*pb2 + u.w*pb3;
        float4 a;
        a.x = EXP2_(lg.x * Av.x); a.y = EXP2_(lg.y * Av.y);
        a.z = EXP2_(lg.z * Av.z); a.w = EXP2_(lg.w * Av.w);
        sv.x = fmaf(a.x, sv.x, lg.x*u.x*Bv);
        sv.y = fmaf(a.y, sv.y, lg.y*u.y*Bv);
        sv.z = fmaf(a.z, sv.z, lg.z*u.z*Bv);
        sv.w = fmaf(a.w, sv.w, lg.w*u.w*Bv);
        ap.x *= a.x; ap.y *= a.y; ap.z *= a.z; ap.w *= a.w;
    }
    long ci = (((long)g*NCHn + chunk)*64 + lane)*4;
    *(float4*)(Ap + ci) = ap;
    *(float4*)(Sv + ci) = sv;
}

// ---------------- 3b. scan phase C (pipelined exclusive prefix) ----------------
#define SCANC_G 8
__global__ __launch_bounds__(256)
void k_scanC(const float* __restrict__ Ap, float* __restrict__ Sv) {
    int g   = blockIdx.x;           // 24 groups
    int tid = threadIdx.x;          // 256 states per group
    long base = (long)g*NCHn*256 + tid;
    const int NFULL = NCHn / SCANC_G;        // 42 full groups
    float h = 0.f;
    float ca[SCANC_G], cs[SCANC_G], na[SCANC_G], ns[SCANC_G];
#pragma unroll
    for (int j = 0; j < SCANC_G; j++) {
        ca[j] = Ap[base + (long)j*256];
        cs[j] = Sv[base + (long)j*256];
    }
    for (int grp = 0; grp < NFULL; grp++) {
        long gb = base + (long)grp*SCANC_G*256;
        if (grp + 1 < NFULL) {
            long nb = gb + (long)SCANC_G*256;
#pragma unroll
            for (int j = 0; j < SCANC_G; j++) {
                na[j] = Ap[nb + (long)j*256];
                ns[j] = Sv[nb + (long)j*256];
            }
        }
#pragma unroll
        for (int j = 0; j < SCANC_G; j++) {
            Sv[gb + (long)j*256] = h;
            h = fmaf(ca[j], h, cs[j]);
        }
#pragma unroll
        for (int j = 0; j < SCANC_G; j++) { ca[j] = na[j]; cs[j] = ns[j]; }
    }
    for (int cc = NFULL*SCANC_G; cc < NCHn; cc++) {
        long ci = base + (long)cc*256;
        float a = Ap[ci];
        float s = Sv[ci];
        Sv[ci] = h;
        h = fmaf(a, h, s);
    }
}

// ---------------- 3c. scan phase D: final scan + y (D-term folded) ----------------
__global__ __launch_bounds__(256, 8)
void k_scanD(const float* __restrict__ rec, float* __restrict__ yb, int l,
             const float* __restrict__ xpw, const float* __restrict__ Alog,
             const float* __restrict__ H0, const float* __restrict__ Dp) {
    int wid  = blockIdx.x*4 + (threadIdx.x >> 6);
    int lane = threadIdx.x & 63;
    int chunk = wid % NCHn;
    int g     = wid / NCHn;
    int m = g >> 3;
    int s = lane >> 4, n = lane & 15;
    int bb = (g & 7)*4 + s;
    int ml = m*NLn + l;
    const float* P  = xpw + (long)ml*33*4;
    const float* PB = P + (1+n)*4;
    float pb0 = PB[0]*LN2_, pb1 = PB[1]*LN2_, pb2 = PB[2]*LN2_, pb3 = PB[3]*LN2_;
    const float* PC = P + (17+n)*4;
    float pc0 = PC[0], pc1 = PC[1], pc2 = PC[2], pc3 = PC[3];
    const float* AL = Alog + (long)ml*64 + n;
    float4 Av;
    Av.x = -EXP2_(AL[0]  * L2E_);
    Av.y = -EXP2_(AL[16] * L2E_);
    Av.z = -EXP2_(AL[32] * L2E_);
    Av.w = -EXP2_(AL[48] * L2E_);
    float Dd = Dp[ml*4 + (n & 3)];
    float4 h = *(const float4*)(H0 + (((long)g*NCHn + chunk)*64 + lane)*4);
    const float* rb = rec + ((long)m*N_BL + (long)bb*LCn)*8;
    float* ym = yb + ((long)m*N_BL + (long)bb*LCn)*4;   // [m][b][t][d]
    int t0 = chunk*CHn;
#pragma unroll 4
    for (int t = t0; t < t0 + CHn; t++) {
        float4 u  = *(const float4*)(rb + (long)t*8);
        float4 lg = *(const float4*)(rb + (long)t*8 + 4);
        float Bv = u.x*pb0 + u.y*pb1 + u.z*pb2 + u.w*pb3;
        float Cv = u.x*pc0 + u.y*pc1 + u.z*pc2 + u.w*pc3;
        float4 a;
        a.x = EXP2_(lg.x * Av.x); a.y = EXP2_(lg.y * Av.y);
        a.z = EXP2_(lg.z * Av.z); a.w = EXP2_(lg.w * Av.w);
        h.x = fmaf(a.x, h.x, lg.x*u.x*Bv);
        h.y = fmaf(a.y, h.y, lg.y*u.y*Bv);
        h.z = fmaf(a.z, h.z, lg.z*u.z*Bv);
        h.w = fmaf(a.w, h.w, lg.w*u.w*Bv);
        float px = rowsum16(h.x * Cv);
        float py = rowsum16(h.y * Cv);
        float pz = rowsum16(h.z * Cv);
        float pw = rowsum16(h.w * Cv);
        if (n < 4) {
            float out = (n & 2) ? ((n & 1) ? pw : pz) : ((n & 1) ? py : px);
            float ud  = sel4(u, n);
            ym[(long)t*4 + n] = fmaf(ud, Dd, out);
        }
    }
}

// ---------------- 4. l=1 post fused with head ----------------
__global__ void k_postHead(const float* __restrict__ hin,
                           const float* __restrict__ yb,
                           const float* __restrict__ ipw, const float* __restrict__ nw,
                           const float* __restrict__ opw,
                           const float* __restrict__ ww, const float* __restrict__ wb,
                           const float* __restrict__ gw, const float* __restrict__ gb,
                           const float* __restrict__ dw, const float* __restrict__ dbp,
                           float* __restrict__ raw, float* __restrict__ dout) {
    long r = (long)blockIdx.x * 256 + threadIdx.x;
    if (r >= N_BL) return;
    float4 om[3];
#pragma unroll
    for (int m = 0; m < 3; m++) {
        int ml = m*NLn + 1;
        float4 hv = *(const float4*)(hin + (long)m*4*N_BL + r*4);
        float ms = (hv.x*hv.x + hv.y*hv.y + hv.z*hv.z + hv.w*hv.w)*0.25f + 1e-5f;
        float rs = __builtin_amdgcn_rsqf(ms);
        const float* wn = nw + ml*4;
        float hn0 = hv.x*rs*wn[0], hn1 = hv.y*rs*wn[1];
        float hn2 = hv.z*rs*wn[2], hn3 = hv.w*rs*wn[3];
        const float* W = ipw + (long)(ml*8 + 4)*4;
        float4 yv = *(const float4*)(yb + ((long)m*N_BL + r)*4);
        float g0 = yv.x * si_(W[0]*hn0  + W[1]*hn1  + W[2]*hn2  + W[3]*hn3);
        float g1 = yv.y * si_(W[4]*hn0  + W[5]*hn1  + W[6]*hn2  + W[7]*hn3);
        float g2 = yv.z * si_(W[8]*hn0  + W[9]*hn1  + W[10]*hn2 + W[11]*hn3);
        float g3 = yv.w * si_(W[12]*hn0 + W[13]*hn1 + W[14]*hn2 + W[15]*hn3);
        const float* O = opw + ml*16;
        float4 o;
        o.x = O[0]*g0  + O[1]*g1  + O[2]*g2  + O[3]*g3  + hv.x;
        o.y = O[4]*g0  + O[5]*g1  + O[6]*g2  + O[7]*g3  + hv.y;
        o.z = O[8]*g0  + O[9]*g1  + O[10]*g2 + O[11]*g3 + hv.z;
        o.w = O[12]*g0 + O[13]*g1 + O[14]*g2 + O[15]*g3 + hv.w;
        om[m] = o;
    }
    float4* c = (float4*)(dout + N_BL + r*12);
    c[0] = om[0]; c[1] = om[1]; c[2] = om[2];
    raw[r]          = om[0].x*ww[0] + om[0].y*ww[1] + om[0].z*ww[2] + om[0].w*ww[3] + wb[0];
    raw[N_BL + r]   = (om[1].x*gw[0] + om[1].y*gw[1] + om[1].z*gw[2] + om[1].w*gw[3] + gb[0]) / 1000.0f;
    raw[2*N_BL + r] = fmaxf(om[2].x*dw[0] + om[2].y*dw[1] + om[2].z*dw[2] + om[2].w*dw[3] + dbp[0], 0.f);
}

// ---------------- 5. smooth + yhat + penalty partials (fused) ----------------
__global__ __launch_bounds__(256)
void k_smoothpen(const float* __restrict__ x, const float* __restrict__ raw,
                 const float* __restrict__ bp, float* __restrict__ dout,
                 double* __restrict__ part) {
    int b    = blockIdx.x >> 5;     // 32 b
    int tile = blockIdx.x & 31;     // 32 tiles of 256
    int k    = threadIdx.x;
    int t0   = tile << 8;
    int t    = t0 + k;
    __shared__ float so_[257], sg_[257], sd_[257];
    const float* ro = raw + (long)b*LCn;
    const float* rg = raw + N_BL   + (long)b*LCn;
    const float* rd = raw + 2*N_BL + (long)b*LCn;
    auto smo3 = [&](int tt, float& o, float& g, float& d) {
        o = g = d = 0.f;
        if (tt < 0 || tt >= LCn) return;
        int lo = max(tt - 4, 0), hi = min(tt + 5, LCn - 1);
        for (int q = lo; q <= hi; q++) {
            o += fabsf(ro[q]); g += rg[q]; d += fabsf(rd[q]);
        }
        o *= 0.1f; g *= 0.1f; d *= 0.1f;
    };
    float so, sg, sd;
    smo3(t, so, sg, sd);
    so_[k] = so; sg_[k] = sg; sd_[k] = sd;
    if (k == 0) {
        float a, bq, cq;
        smo3(t0 + 256, a, bq, cq);
        so_[256] = a; sg_[256] = bq; sd_[256] = cq;
    }
    __syncthreads();
    if (t < LCn) {
        const float* xb = x + (long)b * Ln_;
        const float c0 = 1.f/280.f, c1 = -4.f/105.f, c2 = 0.2f, c3 = -0.8f,
                    c5 = 0.8f, c6 = -0.2f, c7 = 4.f/105.f, c8 = -1.f/280.f;
        float xd  = c0*xb[t]   + c1*xb[t+1] + c2*xb[t+2] + c3*xb[t+3]
                  + c5*xb[t+5] + c6*xb[t+6] + c7*xb[t+7] + c8*xb[t+8];
        float z1 = xb[t+4];
        float z2 = xd / 0.0001f;
        float bq = fmaxf(bp[0], 0.f) / 1000.0f;
        dout[(long)b*LCn + t] = -so*so*z1 + sg*z2 - bq*z1*z1*z2 - sd;
    }
    double v[6] = {0,0,0,0,0,0};
    if (t >= 1 && t <= LCn - 2) {
        double go = (double)so_[k+1] - (double)so_[k];
        double gg = (double)sg_[k+1] - (double)sg_[k];
        double gd = (double)sd_[k+1] - (double)sd_[k];
        v[0] = go; v[1] = go*go;
        v[2] = gg; v[3] = gg*gg;
        v[4] = gd; v[5] = gd*gd;
    }
#pragma unroll
    for (int j = 0; j < 6; j++) {
        for (int off = 32; off > 0; off >>= 1)
            v[j] += __shfl_down(v[j], off, 64);
    }
    __shared__ double wsum[4][6];
    int w = threadIdx.x >> 6;
    if ((threadIdx.x & 63) == 0) {
#pragma unroll
        for (int j = 0; j < 6; j++) wsum[w][j] = v[j];
    }
    __syncthreads();
    if (threadIdx.x == 0) {
        double s[6];
#pragma unroll
        for (int j = 0; j < 6; j++)
            s[j] = wsum[0][j] + wsum[1][j] + wsum[2][j] + wsum[3][j];
        long pb = (((long)0*32 + b)*32 + tile)*2;
        part[pb]   = s[0]; part[pb+1] = s[1];
        pb = (((long)1*32 + b)*32 + tile)*2;
        part[pb]   = s[2]; part[pb+1] = s[3];
        pb = (((long)2*32 + b)*32 + tile)*2;
        part[pb]   = s[4]; part[pb+1] = s[5];
    }
}

// ---------------- 6. penalty finalize ----------------
__global__ void k_pen2(const double* __restrict__ part, float* __restrict__ pout) {
    int tid = threadIdx.x;          // 128 threads, 96 active
    double var = 0.0;
    if (tid < 96) {
        int which = tid / 32, b = tid % 32;
        double su = 0.0, s2 = 0.0;
        for (int tl = 0; tl < 32; tl++) {
            const double* p = part + (((long)which*32 + b)*32 + tl)*2;
            su += p[0]; s2 += p[1];
        }
        const double N = (double)(LCn - 2);
        var = (s2 - su*su/N) / (N - 1.0);
    }
    __shared__ double sh[128];
    sh[tid] = var;
    __syncthreads();
    for (int o = 64; o > 0; o >>= 1) {
        if (tid < o) sh[tid] += sh[tid + o];
        __syncthreads();
    }
    if (tid == 0) pout[0] = (float)(sh[0] / 96.0);
}

// ---------------- launch ----------------
extern "C" void kernel_launch(void* const* d_in, const int* in_sizes, int n_in,
                              void* d_out, int out_size, void* d_ws, size_t ws_size,
                              hipStream_t stream) {
    const float* x    = (const float*)d_in[0];
    const float* ipw  = (const float*)d_in[1];
    const float* cw   = (const float*)d_in[2];
    const float* cbv  = (const float*)d_in[3];
    const float* xpw  = (const float*)d_in[4];
    const float* dtw  = (const float*)d_in[5];
    const float* dtb  = (const float*)d_in[6];
    const float* Alog = (const float*)d_in[7];
    const float* Dp   = (const float*)d_in[8];
    const float* nw   = (const float*)d_in[9];
    const float* opw  = (const float*)d_in[10];
    const float* ww   = (const float*)d_in[11];
    const float* wb   = (const float*)d_in[12];
    const float* gw   = (const float*)d_in[13];
    const float* gb   = (const float*)d_in[14];
    const float* dw   = (const float*)d_in[15];
    const float* dbp  = (const float*)d_in[16];
    const float* bp   = (const float*)d_in[17];

    float* ws   = (float*)d_ws;
    float* h    = ws + OFF_H;
    float* rec  = ws + OFF_REC;
    float* yb   = ws + OFF_YB;
    float* ap   = yb;                 // Ap aliases YB[0,8N) (dead before scanD writes y)
    float* raw  = ws + OFF_RAW;       // aliases rec (dead after scanD l=1)
    double* part = (double*)(ws + OFF_PART);
    float* dout = (float*)d_out;
    float* sv  = dout + 4*N_BL;       // d_out scratch, last read by scanD l=1

    hipLaunchKernelGGL(k_pre0, dim3(3072), dim3(256), 0, stream,
                       x, ipw, cw, cbv, nw, xpw, dtw, dtb, rec);
    hipLaunchKernelGGL(k_scanB, dim3(2046), dim3(256), 0, stream,
                       rec, 0, xpw, Alog, ap, sv);
    hipLaunchKernelGGL(k_scanC, dim3(NGn), dim3(256), 0, stream, ap, sv);
    hipLaunchKernelGGL(k_scanD, dim3(2046), dim3(256), 0, stream,
                       rec, yb, 0, xpw, Alog, sv, Dp);
    hipLaunchKernelGGL(k_mid, dim3(3072), dim3(256), 0, stream,
                       x, yb, h, ipw, cw, cbv, nw, xpw, dtw, dtb, opw, rec);
    hipLaunchKernelGGL(k_scanB, dim3(2046), dim3(256), 0, stream,
                       rec, 1, xpw, Alog, ap, sv);
    hipLaunchKernelGGL(k_scanC, dim3(NGn), dim3(256), 0, stream, ap, sv);
    hipLaunchKernelGGL(k_scanD, dim3(2046), dim3(256), 0, stream,
                       rec, yb, 1, xpw, Alog, sv, Dp);
    hipLaunchKernelGGL(k_postHead, dim3(1023), dim3(256), 0, stream,
                       h, yb, ipw, nw, opw, ww, wb, gw, gb, dw, dbp, raw, dout);
    hipLaunchKernelGGL(k_smoothpen, dim3(1024), dim3(256), 0, stream,
                       x, raw, bp, dout, part);
    hipLaunchKernelGGL(k_pen2, dim3(1), dim3(128), 0, stream, part, dout + 13*N_BL);
}

// Round 15
// 176.957 us; speedup vs baseline: 3.7255x; 1.0047x over previous
//
#include <hip/hip_runtime.h>
#include <math.h>

// ---------------- problem constants ----------------
#define Bn_   32
#define Ln_   8192
#define LCn   8184            // L - 8
#define NLn   2
#define NCHn  341             // scan chunks (341*24 = 8184 exactly, no tail)
#define CHn   24              // chunk length
#define NGn   24              // sequence groups (96 seqs / 4 per wave)

static constexpr long N_BL = (long)Bn_ * LCn;            // 261888

// ---- ws layout (float offsets), total 48N = 50.28 MB ----
static constexpr long OFF_H    = 0;                  // 12N  (mamba hidden, layer-0 output)
static constexpr long OFF_REC  = 12*N_BL;            // 24N  (rec = [u0..3, lg0..3] per (m,b,t))
static constexpr long OFF_YB   = 36*N_BL;            // 12N  (scan y, [m][b][t][d]); Ap aliases first 8N
// aliases over REC (dead after postHead):
static constexpr long OFF_RAW  = OFF_REC;            // 3N
static constexpr long OFF_PART = OFF_REC + 3*N_BL;   // 6144 doubles
// d_out scratch: Sv [4N,12N)  (out_size = 13N+1)

#define L2E_  1.4426950408889634f     // log2(e)
#define LN2_  0.6931471805599453f     // ln(2)
#define EXP2_(x) __builtin_amdgcn_exp2f(x)
#define LOG2_(x) __builtin_amdgcn_logf(x)

__device__ __forceinline__ float si_(float v) {
    float e = EXP2_(-v * L2E_);
    return v * __builtin_amdgcn_rcpf(1.f + e);
}

__device__ __forceinline__ float sel4(float4 v, int d) {
    return (d & 2) ? ((d & 1) ? v.w : v.z) : ((d & 1) ? v.y : v.x);
}

__device__ __forceinline__ float rowsum16(float p) {
    p += __int_as_float(__builtin_amdgcn_update_dpp(0, __float_as_int(p), 0x128, 0xF, 0xF, true)); // row_ror:8
    p += __int_as_float(__builtin_amdgcn_update_dpp(0, __float_as_int(p), 0x124, 0xF, 0xF, true)); // row_ror:4
    p += __int_as_float(__builtin_amdgcn_update_dpp(0, __float_as_int(p), 0x122, 0xF, 0xF, true)); // row_ror:2
    p += __int_as_float(__builtin_amdgcn_update_dpp(0, __float_as_int(p), 0x121, 0xF, 0xF, true)); // row_ror:1
    return p;
}

// xin(p) = [z0, xd, z0_flip, xd_flip] recomputed from x (x is 1MB -> L2-hot)
__device__ __forceinline__ float4 compute_xin(const float* __restrict__ xb, int p) {
    const float c0 = 1.f/280.f, c1 = -4.f/105.f, c2 = 0.2f, c3 = -0.8f,
                c5 = 0.8f, c6 = -0.2f, c7 = 4.f/105.f, c8 = -1.f/280.f;
    float xd  = c0*xb[p]   + c1*xb[p+1] + c2*xb[p+2] + c3*xb[p+3]
              + c5*xb[p+5] + c6*xb[p+6] + c7*xb[p+7] + c8*xb[p+8];
    int tf = LCn - 1 - p;
    float xdf = c0*xb[tf]   + c1*xb[tf+1] + c2*xb[tf+2] + c3*xb[tf+3]
              + c5*xb[tf+5] + c6*xb[tf+6] + c7*xb[tf+7] + c8*xb[tf+8];
    float4 v; v.x = xb[p+4]; v.y = xd; v.z = xb[tf+4]; v.w = xdf;
    return v;
}

__device__ __forceinline__ float4 rms_xproj(float4 hv, const float* __restrict__ wn,
                                            const float* __restrict__ W) {
    float ms = (hv.x*hv.x + hv.y*hv.y + hv.z*hv.z + hv.w*hv.w)*0.25f + 1e-5f;
    float rs = __builtin_amdgcn_rsqf(ms);
    float hn0 = hv.x*rs*wn[0], hn1 = hv.y*rs*wn[1];
    float hn2 = hv.z*rs*wn[2], hn3 = hv.w*rs*wn[3];
    float4 o;
    o.x = W[0]*hn0  + W[1]*hn1  + W[2]*hn2  + W[3]*hn3;
    o.y = W[4]*hn0  + W[5]*hn1  + W[6]*hn2  + W[7]*hn3;
    o.z = W[8]*hn0  + W[9]*hn1  + W[10]*hn2 + W[11]*hn3;
    o.w = W[12]*hn0 + W[13]*hn1 + W[14]*hn2 + W[15]*hn3;
    return o;
}

__device__ __forceinline__ void conv_lg_store(const float4* xp, int k, int ml,
                                              const float* __restrict__ cw,
                                              const float* __restrict__ cbv,
                                              const float* __restrict__ xpw,
                                              const float* __restrict__ dtw,
                                              const float* __restrict__ dtb,
                                              float* __restrict__ rp) {
    const float* wc = cw  + ml*16;
    const float* bc = cbv + ml*4;
    float acc0 = bc[0], acc1 = bc[1], acc2 = bc[2], acc3 = bc[3];
#pragma unroll
    for (int j = 0; j < 4; j++) {
        float4 xv = xp[k + j];
        acc0 = fmaf(xv.x, wc[0*4+j], acc0);
        acc1 = fmaf(xv.y, wc[1*4+j], acc1);
        acc2 = fmaf(xv.z, wc[2*4+j], acc2);
        acc3 = fmaf(xv.w, wc[3*4+j], acc3);
    }
    float4 o;
    o.x = si_(acc0); o.y = si_(acc1); o.z = si_(acc2); o.w = si_(acc3);
    const float* P = xpw + (long)ml*33*4;
    float dtr = o.x*P[0] + o.y*P[1] + o.z*P[2] + o.w*P[3];
    const float* dwv = dtw + ml*4;
    const float* dbv = dtb + ml*4;
    float4 lg;
    lg.x = LOG2_(1.f + EXP2_(fmaf(dtr, dwv[0], dbv[0]) * L2E_));
    lg.y = LOG2_(1.f + EXP2_(fmaf(dtr, dwv[1], dbv[1]) * L2E_));
    lg.z = LOG2_(1.f + EXP2_(fmaf(dtr, dwv[2], dbv[2]) * L2E_));
    lg.w = LOG2_(1.f + EXP2_(fmaf(dtr, dwv[3], dbv[3]) * L2E_));
    *(float4*)rp       = o;
    *(float4*)(rp + 4) = lg;
}

// ---------------- 1. fused deriv + rmsnorm0 + in_proj0 + conv0 + silu + lg ----------------
__global__ __launch_bounds__(256)
void k_pre0(const float* __restrict__ x,
            const float* __restrict__ ipw, const float* __restrict__ cw,
            const float* __restrict__ cbv, const float* __restrict__ nw,
            const float* __restrict__ xpw, const float* __restrict__ dtw,
            const float* __restrict__ dtb, float* __restrict__ rec) {
    __shared__ float4 xp[259];
    int blk = blockIdx.x;
    int m = blk >> 10, bb = (blk >> 5) & 31, tile = blk & 31;
    int ml = m*NLn;                 // l = 0
    int t0 = tile << 8, k = threadIdx.x;
    int t  = t0 + k;
    const float* xb = x + (long)bb*Ln_;
    const float* W  = ipw + (long)ml*32;
    const float* wn = nw  + ml*4;
    auto G = [&](int p) -> float4 {
        float4 o; o.x = o.y = o.z = o.w = 0.f;
        if (p >= 0 && p < LCn) o = rms_xproj(compute_xin(xb, p), wn, W);
        return o;
    };
    xp[k + 3] = G(t);
    if (k < 3) xp[k] = G(t0 + k - 3);
    __syncthreads();
    if (t >= LCn) return;
    conv_lg_store(xp, k, ml, cw, cbv, xpw, dtw, dtb,
                  rec + ((long)m*N_BL + (long)bb*LCn + t)*8);
}

// ---------------- 2. fused post0 (writes h) + rmsnorm1 + in_proj1 + conv1 + silu + lg ----------------
__global__ __launch_bounds__(256)
void k_mid(const float* __restrict__ x, const float* __restrict__ yb,
           float* __restrict__ hout,
           const float* __restrict__ ipw, const float* __restrict__ cw,
           const float* __restrict__ cbv, const float* __restrict__ nw,
           const float* __restrict__ xpw, const float* __restrict__ dtw,
           const float* __restrict__ dtb, const float* __restrict__ opw,
           float* __restrict__ rec) {
    __shared__ float4 xp[259];
    int blk = blockIdx.x;
    int m = blk >> 10, bb = (blk >> 5) & 31, tile = blk & 31;
    int ml0 = m*NLn, ml1 = ml0 + 1;
    int t0 = tile << 8, k = threadIdx.x;
    int t  = t0 + k;
    const float* xb  = x + (long)bb*Ln_;
    const float* wn0 = nw + ml0*4;
    const float* Wr  = ipw + (long)(ml0*8 + 4)*4;
    const float* O   = opw + ml0*16;
    const float* wn1 = nw + ml1*4;
    const float* W1  = ipw + (long)ml1*32;
    auto H = [&](int p) -> float4 {
        float4 hv = compute_xin(xb, p);
        float ms = (hv.x*hv.x + hv.y*hv.y + hv.z*hv.z + hv.w*hv.w)*0.25f + 1e-5f;
        float rs = __builtin_amdgcn_rsqf(ms);
        float hn0 = hv.x*rs*wn0[0], hn1 = hv.y*rs*wn0[1];
        float hn2 = hv.z*rs*wn0[2], hn3 = hv.w*rs*wn0[3];
        float4 yv = *(const float4*)(yb + ((long)m*N_BL + (long)bb*LCn + p)*4);
        float g0 = yv.x * si_(Wr[0]*hn0  + Wr[1]*hn1  + Wr[2]*hn2  + Wr[3]*hn3);
        float g1 = yv.y * si_(Wr[4]*hn0  + Wr[5]*hn1  + Wr[6]*hn2  + Wr[7]*hn3);
        float g2 = yv.z * si_(Wr[8]*hn0  + Wr[9]*hn1  + Wr[10]*hn2 + Wr[11]*hn3);
        float g3 = yv.w * si_(Wr[12]*hn0 + Wr[13]*hn1 + Wr[14]*hn2 + Wr[15]*hn3);
        float4 o;
        o.x = O[0]*g0  + O[1]*g1  + O[2]*g2  + O[3]*g3  + hv.x;
        o.y = O[4]*g0  + O[5]*g1  + O[6]*g2  + O[7]*g3  + hv.y;
        o.z = O[8]*g0  + O[9]*g1  + O[10]*g2 + O[11]*g3 + hv.z;
        o.w = O[12]*g0 + O[13]*g1 + O[14]*g2 + O[15]*g3 + hv.w;
        return o;
    };
    float4 zf; zf.x = zf.y = zf.z = zf.w = 0.f;
    if (t < LCn) {
        float4 hnew = H(t);
        *(float4*)(hout + ((long)m*N_BL + (long)bb*LCn + t)*4) = hnew;
        xp[k + 3] = rms_xproj(hnew, wn1, W1);
    } else {
        xp[k + 3] = zf;
    }
    if (k < 3) {
        int p = t0 + k - 3;
        xp[k] = (p >= 0) ? rms_xproj(H(p), wn1, W1) : zf;
    }
    __syncthreads();
    if (t >= LCn) return;
    conv_lg_store(xp, k, ml1, cw, cbv, xpw, dtw, dtb,
                  rec + ((long)m*N_BL + (long)bb*LCn + t)*8);
}

// ---------------- 3a. scan phase B ----------------
__global__ __launch_bounds__(256, 8)
void k_scanB(const float* __restrict__ rec, int l,
             const float* __restrict__ xpw, const float* __restrict__ Alog,
             float* __restrict__ Ap, float* __restrict__ Sv) {
    int wid  = blockIdx.x*4 + (threadIdx.x >> 6);
    int lane = threadIdx.x & 63;
    int chunk = wid % NCHn;
    int g     = wid / NCHn;         // 0..23
    int m = g >> 3;
    int s = lane >> 4, n = lane & 15;
    int bb = (g & 7)*4 + s;
    int ml = m*NLn + l;
    const float* P  = xpw + (long)ml*33*4;
    const float* PB = P + (1+n)*4;
    float pb0 = PB[0]*LN2_, pb1 = PB[1]*LN2_, pb2 = PB[2]*LN2_, pb3 = PB[3]*LN2_;
    const float* AL = Alog + (long)ml*64 + n;
    float4 Av;
    Av.x = -EXP2_(AL[0]  * L2E_);
    Av.y = -EXP2_(AL[16] * L2E_);
    Av.z = -EXP2_(AL[32] * L2E_);
    Av.w = -EXP2_(AL[48] * L2E_);
    const float* rb = rec + ((long)m*N_BL + (long)bb*LCn)*8;
    int t0 = chunk*CHn;
    float4 ap; ap.x = ap.y = ap.z = ap.w = 1.f;
    float4 sv; sv.x = sv.y = sv.z = sv.w = 0.f;
#pragma unroll 4
    for (int t = t0; t < t0 + CHn; t++) {
        float4 u  = *(const float4*)(rb + (long)t*8);
        float4 lg = *(const float4*)(rb + (long)t*8 + 4);
        float Bv = u.x*pb0 + u.y*pb1 + u.z*pb2 + u.w*pb3;
        float4 a;
        a.x = EXP2_(lg.x * Av.x); a.y = EXP2_(lg.y * Av.y);
        a.z = EXP2_(lg.z * Av.z); a.w = EXP2_(lg.w * Av.w);
        sv.x = fmaf(a.x, sv.x, lg.x*u.x*Bv);
        sv.y = fmaf(a.y, sv.y, lg.y*u.y*Bv);
        sv.z = fmaf(a.z, sv.z, lg.z*u.z*Bv);
        sv.w = fmaf(a.w, sv.w, lg.w*u.w*Bv);
        ap.x *= a.x; ap.y *= a.y; ap.z *= a.z; ap.w *= a.w;
    }
    long ci = (((long)g*NCHn + chunk)*64 + lane)*4;
    *(float4*)(Ap + ci) = ap;
    *(float4*)(Sv + ci) = sv;
}

// ---------------- 3b. scan phase C (pipelined exclusive prefix) ----------------
#define SCANC_G 8
__global__ __launch_bounds__(256)
void k_scanC(const float* __restrict__ Ap, float* __restrict__ Sv) {
    int g   = blockIdx.x;           // 24 groups
    int tid = threadIdx.x;          // 256 states per group
    long base = (long)g*NCHn*256 + tid;
    const int NFULL = NCHn / SCANC_G;        // 42 full groups
    float h = 0.f;
    float ca[SCANC_G], cs[SCANC_G], na[SCANC_G], ns[SCANC_G];
#pragma unroll
    for (int j = 0; j < SCANC_G; j++) {
        ca[j] = Ap[base + (long)j*256];
        cs[j] = Sv[base + (long)j*256];
    }
    for (int grp = 0; grp < NFULL; grp++) {
        long gb = base + (long)grp*SCANC_G*256;
        if (grp + 1 < NFULL) {
            long nb = gb + (long)SCANC_G*256;
#pragma unroll
            for (int j = 0; j < SCANC_G; j++) {
                na[j] = Ap[nb + (long)j*256];
                ns[j] = Sv[nb + (long)j*256];
            }
        }
#pragma unroll
        for (int j = 0; j < SCANC_G; j++) {
            Sv[gb + (long)j*256] = h;
            h = fmaf(ca[j], h, cs[j]);
        }
#pragma unroll
        for (int j = 0; j < SCANC_G; j++) { ca[j] = na[j]; cs[j] = ns[j]; }
    }
    for (int cc = NFULL*SCANC_G; cc < NCHn; cc++) {
        long ci = base + (long)cc*256;
        float a = Ap[ci];
        float s = Sv[ci];
        Sv[ci] = h;
        h = fmaf(a, h, s);
    }
}

// ---------------- 3c. scan phase D: final scan + y (D-term folded) ----------------
__global__ __launch_bounds__(256, 8)
void k_scanD(const float* __restrict__ rec, float* __restrict__ yb, int l,
             const float* __restrict__ xpw, const float* __restrict__ Alog,
             const float* __restrict__ H0, const float* __restrict__ Dp) {
    int wid  = blockIdx.x*4 + (threadIdx.x >> 6);
    int lane = threadIdx.x & 63;
    int chunk = wid % NCHn;
    int g     = wid / NCHn;
    int m = g >> 3;
    int s = lane >> 4, n = lane & 15;
    int bb = (g & 7)*4 + s;
    int ml = m*NLn + l;
    const float* P  = xpw + (long)ml*33*4;
    const float* PB = P + (1+n)*4;
    float pb0 = PB[0]*LN2_, pb1 = PB[1]*LN2_, pb2 = PB[2]*LN2_, pb3 = PB[3]*LN2_;
    const float* PC = P + (17+n)*4;
    float pc0 = PC[0], pc1 = PC[1], pc2 = PC[2], pc3 = PC[3];
    const float* AL = Alog + (long)ml*64 + n;
    float4 Av;
    Av.x = -EXP2_(AL[0]  * L2E_);
    Av.y = -EXP2_(AL[16] * L2E_);
    Av.z = -EXP2_(AL[32] * L2E_);
    Av.w = -EXP2_(AL[48] * L2E_);
    float Dd = Dp[ml*4 + (n & 3)];
    float4 h = *(const float4*)(H0 + (((long)g*NCHn + chunk)*64 + lane)*4);
    const float* rb = rec + ((long)m*N_BL + (long)bb*LCn)*8;
    float* ym = yb + ((long)m*N_BL + (long)bb*LCn)*4;   // [m][b][t][d]
    int t0 = chunk*CHn;
#pragma unroll 4
    for (int t = t0; t < t0 + CHn; t++) {
        float4 u  = *(const float4*)(rb + (long)t*8);
        float4 lg = *(const float4*)(rb + (long)t*8 + 4);
        float Bv = u.x*pb0 + u.y*pb1 + u.z*pb2 + u.w*pb3;
        float Cv = u.x*pc0 + u.y*pc1 + u.z*pc2 + u.w*pc3;
        float4 a;
        a.x = EXP2_(lg.x * Av.x); a.y = EXP2_(lg.y * Av.y);
        a.z = EXP2_(lg.z * Av.z); a.w = EXP2_(lg.w * Av.w);
        h.x = fmaf(a.x, h.x, lg.x*u.x*Bv);
        h.y = fmaf(a.y, h.y, lg.y*u.y*Bv);
        h.z = fmaf(a.z, h.z, lg.z*u.z*Bv);
        h.w = fmaf(a.w, h.w, lg.w*u.w*Bv);
        float px = rowsum16(h.x * Cv);
        float py = rowsum16(h.y * Cv);
        float pz = rowsum16(h.z * Cv);
        float pw = rowsum16(h.w * Cv);
        if (n < 4) {
            float out = (n & 2) ? ((n & 1) ? pw : pz) : ((n & 1) ? py : px);
            float ud  = sel4(u, n);
            ym[(long)t*4 + n] = fmaf(ud, Dd, out);
        }
    }
}

// ---------------- 4. l=1 post fused with head ----------------
__global__ void k_postHead(const float* __restrict__ hin,
                           const float* __restrict__ yb,
                           const float* __restrict__ ipw, const float* __restrict__ nw,
                           const float* __restrict__ opw,
                           const float* __restrict__ ww, const float* __restrict__ wb,
                           const float* __restrict__ gw, const float* __restrict__ gb,
                           const float* __restrict__ dw, const float* __restrict__ dbp,
                           float* __restrict__ raw, float* __restrict__ dout) {
    long r = (long)blockIdx.x * 256 + threadIdx.x;
    if (r >= N_BL) return;
    float4 om[3];
#pragma unroll
    for (int m = 0; m < 3; m++) {
        int ml = m*NLn + 1;
        float4 hv = *(const float4*)(hin + (long)m*4*N_BL + r*4);
        float ms = (hv.x*hv.x + hv.y*hv.y + hv.z*hv.z + hv.w*hv.w)*0.25f + 1e-5f;
        float rs = __builtin_amdgcn_rsqf(ms);
        const float* wn = nw + ml*4;
        float hn0 = hv.x*rs*wn[0], hn1 = hv.y*rs*wn[1];
        float hn2 = hv.z*rs*wn[2], hn3 = hv.w*rs*wn[3];
        const float* W = ipw + (long)(ml*8 + 4)*4;
        float4 yv = *(const float4*)(yb + ((long)m*N_BL + r)*4);
        float g0 = yv.x * si_(W[0]*hn0  + W[1]*hn1  + W[2]*hn2  + W[3]*hn3);
        float g1 = yv.y * si_(W[4]*hn0  + W[5]*hn1  + W[6]*hn2  + W[7]*hn3);
        float g2 = yv.z * si_(W[8]*hn0  + W[9]*hn1  + W[10]*hn2 + W[11]*hn3);
        float g3 = yv.w * si_(W[12]*hn0 + W[13]*hn1 + W[14]*hn2 + W[15]*hn3);
        const float* O = opw + ml*16;
        float4 o;
        o.x = O[0]*g0  + O[1]*g1  + O[2]*g2  + O[3]*g3  + hv.x;
        o.y = O[4]*g0  + O[5]*g1  + O[6]*g2  + O[7]*g3  + hv.y;
        o.z = O[8]*g0  + O[9]*g1  + O[10]*g2 + O[11]*g3 + hv.z;
        o.w = O[12]*g0 + O[13]*g1 + O[14]*g2 + O[15]*g3 + hv.w;
        om[m] = o;
    }
    float4* c = (float4*)(dout + N_BL + r*12);
    c[0] = om[0]; c[1] = om[1]; c[2] = om[2];
    raw[r]          = om[0].x*ww[0] + om[0].y*ww[1] + om[0].z*ww[2] + om[0].w*ww[3] + wb[0];
    raw[N_BL + r]   = (om[1].x*gw[0] + om[1].y*gw[1] + om[1].z*gw[2] + om[1].w*gw[3] + gb[0]) / 1000.0f;
    raw[2*N_BL + r] = fmaxf(om[2].x*dw[0] + om[2].y*dw[1] + om[2].z*dw[2] + om[2].w*dw[3] + dbp[0], 0.f);
}

// ---------------- 5. smooth + yhat + penalty partials (fused) ----------------
__global__ __launch_bounds__(256)
void k_smoothpen(const float* __restrict__ x, const float* __restrict__ raw,
                 const float* __restrict__ bp, float* __restrict__ dout,
                 double* __restrict__ part) {
    int b    = blockIdx.x >> 5;     // 32 b
    int tile = blockIdx.x & 31;     // 32 tiles of 256
    int k    = threadIdx.x;
    int t0   = tile << 8;
    int t    = t0 + k;
    __shared__ float so_[257], sg_[257], sd_[257];
    const float* ro = raw + (long)b*LCn;
    const float* rg = raw + N_BL   + (long)b*LCn;
    const float* rd = raw + 2*N_BL + (long)b*LCn;
    auto smo3 = [&](int tt, float& o, float& g, float& d) {
        o = g = d = 0.f;
        if (tt < 0 || tt >= LCn) return;
        int lo = max(tt - 4, 0), hi = min(tt + 5, LCn - 1);
        for (int q = lo; q <= hi; q++) {
            o += fabsf(ro[q]); g += rg[q]; d += fabsf(rd[q]);
        }
        o *= 0.1f; g *= 0.1f; d *= 0.1f;
    };
    float so, sg, sd;
    smo3(t, so, sg, sd);
    so_[k] = so; sg_[k] = sg; sd_[k] = sd;
    if (k == 0) {
        float a, bq, cq;
        smo3(t0 + 256, a, bq, cq);
        so_[256] = a; sg_[256] = bq; sd_[256] = cq;
    }
    __syncthreads();
    if (t < LCn) {
        const float* xb = x + (long)b * Ln_;
        const float c0 = 1.f/280.f, c1 = -4.f/105.f, c2 = 0.2f, c3 = -0.8f,
                    c5 = 0.8f, c6 = -0.2f, c7 = 4.f/105.f, c8 = -1.f/280.f;
        float xd  = c0*xb[t]   + c1*xb[t+1] + c2*xb[t+2] + c3*xb[t+3]
                  + c5*xb[t+5] + c6*xb[t+6] + c7*xb[t+7] + c8*xb[t+8];
        float z1 = xb[t+4];
        float z2 = xd / 0.0001f;
        float bq = fmaxf(bp[0], 0.f) / 1000.0f;
        dout[(long)b*LCn + t] = -so*so*z1 + sg*z2 - bq*z1*z1*z2 - sd;
    }
    double v[6] = {0,0,0,0,0,0};
    if (t >= 1 && t <= LCn - 2) {
        double go = (double)so_[k+1] - (double)so_[k];
        double gg = (double)sg_[k+1] - (double)sg_[k];
        double gd = (double)sd_[k+1] - (double)sd_[k];
        v[0] = go; v[1] = go*go;
        v[2] = gg; v[3] = gg*gg;
        v[4] = gd; v[5] = gd*gd;
    }
#pragma unroll
    for (int j = 0; j < 6; j++) {
        for (int off = 32; off > 0; off >>= 1)
            v[j] += __shfl_down(v[j], off, 64);
    }
    __shared__ double wsum[4][6];
    int w = threadIdx.x >> 6;
    if ((threadIdx.x & 63) == 0) {
#pragma unroll
        for (int j = 0; j < 6; j++) wsum[w][j] = v[j];
    }
    __syncthreads();
    if (threadIdx.x == 0) {
        double s[6];
#pragma unroll
        for (int j = 0; j < 6; j++)
            s[j] = wsum[0][j] + wsum[1][j] + wsum[2][j] + wsum[3][j];
        long pb = (((long)0*32 + b)*32 + tile)*2;
        part[pb]   = s[0]; part[pb+1] = s[1];
        pb = (((long)1*32 + b)*32 + tile)*2;
        part[pb]   = s[2]; part[pb+1] = s[3];
        pb = (((long)2*32 + b)*32 + tile)*2;
        part[pb]   = s[4]; part[pb+1] = s[5];
    }
}

// ---------------- 6. penalty finalize ----------------
__global__ void k_pen2(const double* __restrict__ part, float* __restrict__ pout) {
    int tid = threadIdx.x;          // 128 threads, 96 active
    double var = 0.0;
    if (tid < 96) {
        int which = tid / 32, b = tid % 32;
        double su = 0.0, s2 = 0.0;
        for (int tl = 0; tl < 32; tl++) {
            const double* p = part + (((long)which*32 + b)*32 + tl)*2;
            su += p[0]; s2 += p[1];
        }
        const double N = (double)(LCn - 2);
        var = (s2 - su*su/N) / (N - 1.0);
    }
    __shared__ double sh[128];
    sh[tid] = var;
    __syncthreads();
    for (int o = 64; o > 0; o >>= 1) {
        if (tid < o) sh[tid] += sh[tid + o];
        __syncthreads();
    }
    if (tid == 0) pout[0] = (float)(sh[0] / 96.0);
}

// ---------------- launch ----------------
extern "C" void kernel_launch(void* const* d_in, const int* in_sizes, int n_in,
                              void* d_out, int out_size, void* d_ws, size_t ws_size,
                              hipStream_t stream) {
    const float* x    = (const float*)d_in[0];
    const float* ipw  = (const float*)d_in[1];
    const float* cw   = (const float*)d_in[2];
    const float* cbv  = (const float*)d_in[3];
    const float* xpw  = (const float*)d_in[4];
    const float* dtw  = (const float*)d_in[5];
    const float* dtb  = (const float*)d_in[6];
    const float* Alog = (const float*)d_in[7];
    const float* Dp   = (const float*)d_in[8];
    const float* nw   = (const float*)d_in[9];
    const float* opw  = (const float*)d_in[10];
    const float* ww   = (const float*)d_in[11];
    const float* wb   = (const float*)d_in[12];
    const float* gw   = (const float*)d_in[13];
    const float* gb   = (const float*)d_in[14];
    const float* dw   = (const float*)d_in[15];
    const float* dbp  = (const float*)d_in[16];
    const float* bp   = (const float*)d_in[17];

    float* ws   = (float*)d_ws;
    float* h    = ws + OFF_H;
    float* rec  = ws + OFF_REC;
    float* yb   = ws + OFF_YB;
    float* ap   = yb;                 // Ap aliases YB[0,8N) (dead before scanD writes y)
    float* raw  = ws + OFF_RAW;       // aliases rec (dead after scanD l=1)
    double* part = (double*)(ws + OFF_PART);
    float* dout = (float*)d_out;
    float* sv  = dout + 4*N_BL;       // d_out scratch, last read by scanD l=1

    hipLaunchKernelGGL(k_pre0, dim3(3072), dim3(256), 0, stream,
                       x, ipw, cw, cbv, nw, xpw, dtw, dtb, rec);
    hipLaunchKernelGGL(k_scanB, dim3(2046), dim3(256), 0, stream,
                       rec, 0, xpw, Alog, ap, sv);
    hipLaunchKernelGGL(k_scanC, dim3(NGn), dim3(256), 0, stream, ap, sv);
    hipLaunchKernelGGL(k_scanD, dim3(2046), dim3(256), 0, stream,
                       rec, yb, 0, xpw, Alog, sv, Dp);
    hipLaunchKernelGGL(k_mid, dim3(3072), dim3(256), 0, stream,
                       x, yb, h, ipw, cw, cbv, nw, xpw, dtw, dtb, opw, rec);
    hipLaunchKernelGGL(k_scanB, dim3(2046), dim3(256), 0, stream,
                       rec, 1, xpw, Alog, ap, sv);
    hipLaunchKernelGGL(k_scanC, dim3(NGn), dim3(256), 0, stream, ap, sv);
    hipLaunchKernelGGL(k_scanD, dim3(2046), dim3(256), 0, stream,
                       rec, yb, 1, xpw, Alog, sv, Dp);
    hipLaunchKernelGGL(k_postHead, dim3(1023), dim3(256), 0, stream,
                       h, yb, ipw, nw, opw, ww, wb, gw, gb, dw, dbp, raw, dout);
    hipLaunchKernelGGL(k_smoothpen, dim3(1024), dim3(256), 0, stream,
                       x, raw, bp, dout, part);
    hipLaunchKernelGGL(k_pen2, dim3(1), dim3(128), 0, stream, part, dout + 13*N_BL);
}